// Round 7
// baseline (244.741 us; speedup 1.0000x reference)
//
#include <hip/hip_runtime.h>
#include <math.h>

#define NN 1024
#define NBB 16
#define NP 256
#define TT 80
#define EPS_LEN 1e-9f
#define EPS_DD 1e-12f

__device__ __forceinline__ float frcp(float x){ return __builtin_amdgcn_rcpf(x); }
__device__ __forceinline__ float fsq(float x){ return __builtin_amdgcn_sqrtf(x); }
__device__ __forceinline__ float rfl_f(float x){
  return __builtin_bit_cast(float, __builtin_amdgcn_readfirstlane(__builtin_bit_cast(int, x)));
}
__device__ __forceinline__ float rlane_f(float x, int l){
  return __builtin_bit_cast(float, __builtin_amdgcn_readlane(__builtin_bit_cast(int, x), l));
}

// ---- DPP wave64 primitives (canonical gfx9 sequence) ----
template<int CTRL,int RM>
__device__ __forceinline__ float dpp_add(float v){
  int t = __builtin_amdgcn_update_dpp(0, __builtin_bit_cast(int, v), CTRL, RM, 0xf, true);
  return v + __builtin_bit_cast(float, t);
}
__device__ __forceinline__ float wave_incl_scan(float v){
  v = dpp_add<0x111,0xf>(v);   // row_shr:1
  v = dpp_add<0x112,0xf>(v);   // row_shr:2
  v = dpp_add<0x114,0xf>(v);   // row_shr:4
  v = dpp_add<0x118,0xf>(v);   // row_shr:8
  v = dpp_add<0x142,0xa>(v);   // row_bcast:15 -> rows 1,3
  v = dpp_add<0x143,0xc>(v);   // row_bcast:31 -> rows 2,3
  return v;
}
template<int CTRL,int RM>
__device__ __forceinline__ float dpp_min(float v){
  int t = __builtin_amdgcn_update_dpp(0x7f800000, __builtin_bit_cast(int,v), CTRL, RM, 0xf, false);
  return fminf(v, __builtin_bit_cast(float,t));
}
__device__ __forceinline__ float wave_min_all(float v){
  v=dpp_min<0x111,0xf>(v); v=dpp_min<0x112,0xf>(v);
  v=dpp_min<0x114,0xf>(v); v=dpp_min<0x118,0xf>(v);
  v=dpp_min<0x142,0xa>(v); v=dpp_min<0x143,0xc>(v);
  return rlane_f(v, 63);     // lane 63 holds global min
}

// Wave-synchronous LDS fence (LDS partitioned per wave; no __syncthreads).
__device__ __forceinline__ void lds_fence() {
  __builtin_amdgcn_wave_barrier();
  asm volatile("s_waitcnt lgkmcnt(0)" ::: "memory");
  __builtin_amdgcn_wave_barrier();
}

// n_valid, wave-wide. Mask layout auto-detect: byte[1] of buffer != 0 -> bool
// bytes (mask[0][0][1] true since lengths>=2); int32 layout -> that byte is 0.
__device__ __forceinline__ int wave_nv(const void* mask, size_t base, int lane) {
  bool as_byte = ((const unsigned char*)mask)[1] != 0;
  int nv = 0;
  if (as_byte) {
    uchar4 v = ((const uchar4*)((const unsigned char*)mask + base))[lane];
    nv += __popcll(__ballot(v.x != 0));
    nv += __popcll(__ballot(v.y != 0));
    nv += __popcll(__ballot(v.z != 0));
    nv += __popcll(__ballot(v.w != 0));
  } else {
    int4 v = ((const int4*)((const int*)mask + base))[lane];
    nv += __popcll(__ballot(v.x != 0));
    nv += __popcll(__ballot(v.y != 0));
    nv += __popcll(__ballot(v.z != 0));
    nv += __popcll(__ballot(v.w != 0));
  }
  return nv;
}

// Count of entries in cs[0..255] that are (< v) if STRICT else (<= v).
// co[16] are wave-uniform (SGPR) coarse values co[k] = cs[16k+15].
template<bool STRICT>
__device__ __forceinline__ int count256(const float* __restrict__ cs,
                                        const float* co, float v){
  int K = 0;
  #pragma unroll
  for (int k=0;k<16;k++) K += STRICT ? (co[k] < v) : (co[k] <= v);
  int base = (K < 16 ? K : 15) * 16;
  const float4* f4 = (const float4*)(cs + base);
  float4 c0=f4[0], c1=f4[1], c2=f4[2], c3=f4[3];
  int r;
  if (STRICT)
    r = (c0.x<v)+(c0.y<v)+(c0.z<v)+(c0.w<v)+(c1.x<v)+(c1.y<v)+(c1.z<v)+(c1.w<v)
      + (c2.x<v)+(c2.y<v)+(c2.z<v)+(c2.w<v)+(c3.x<v)+(c3.y<v)+(c3.z<v)+(c3.w<v);
  else
    r = (c0.x<=v)+(c0.y<=v)+(c0.z<=v)+(c0.w<=v)+(c1.x<=v)+(c1.y<=v)+(c1.z<=v)+(c1.w<=v)
      + (c2.x<=v)+(c2.y<=v)+(c2.z<=v)+(c2.w<=v)+(c3.x<=v)+(c3.y<=v)+(c3.z<=v)+(c3.w<=v);
  return (K >= 16) ? 256 : (base + r);
}

struct SegOut {
  float cpre[4];
  float run;
  float bdf, btf; int bjf;   // per-lane first-min (fwd)
  float bdl, btl; int bjl;   // per-lane last-min  (rev)
};

// Per-candidate segment pass. Lanes with j0 >= nv skip their point loads
// (those points are never read: interpolation indices stay <= nv-1).
__device__ __forceinline__ void seg_pass(const float4* __restrict__ p4, int lane, int nv,
                                         float p0x, float p0y, float p0z,
                                         float* __restrict__ px, float* __restrict__ py,
                                         float* __restrict__ pz, SegOut& R) {
  const int j0 = lane * 4;
  float4 A = make_float4(0.f,0.f,0.f,0.f), B = A, C = A;
  if (j0 < nv) { A = p4[lane*3+0]; B = p4[lane*3+1]; C = p4[lane*3+2]; }
  float x[5], y[5], z[5];
  x[0]=A.x; y[0]=A.y; z[0]=A.z;
  x[1]=A.w; y[1]=B.x; z[1]=B.y;
  x[2]=B.z; y[2]=B.w; z[2]=C.x;
  x[3]=C.y; y[3]=C.z; z[3]=C.w;
  x[4]=__shfl_down(x[0],1,64); y[4]=__shfl_down(y[0],1,64); z[4]=__shfl_down(z[0],1,64);
  ((float4*)px)[lane] = make_float4(x[0],x[1],x[2],x[3]);
  ((float4*)py)[lane] = make_float4(y[0],y[1],y[2],y[3]);
  ((float4*)pz)[lane] = make_float4(z[0],z[1],z[2],z[3]);
  float run = 0.f;
  R.bdf=INFINITY; R.btf=0.f; R.bjf=j0;
  R.bdl=INFINITY; R.btl=0.f; R.bjl=j0;
  #pragma unroll
  for (int k=0;k<4;k++){
    bool valid = (j0+k) < nv-1;
    float vx=x[k+1]-x[k], vy=y[k+1]-y[k], vz=z[k+1]-z[k];
    float n2 = vx*vx+vy*vy+vz*vz;
    float sl = valid ? fmaxf(fsq(n2), EPS_LEN) : 0.f;
    float t = ((p0x-x[k])*vx+(p0y-y[k])*vy+(p0z-z[k])*vz) * frcp(fmaxf(n2,EPS_DD));
    t = fminf(fmaxf(t,0.f),1.f);
    float qx=x[k]+t*vx, qy=y[k]+t*vy, qz=z[k]+t*vz;
    float dx=p0x-qx, dy=p0y-qy, dz=p0z-qz;
    float d2 = valid ? (dx*dx+dy*dy+dz*dz) : INFINITY;
    if (d2 <  R.bdf){R.bdf=d2; R.bjf=j0+k; R.btf=t;}
    if (d2 <= R.bdl){R.bdl=d2; R.bjl=j0+k; R.btl=t;}
    run += sl; R.cpre[k]=run;
  }
  R.run = run;
}

// One wave evaluates one (n,b), both directions fused.
// MODE 0: returns costs in cf/cr (all lanes).  MODE 1: writes dir=wdir proj to out.
template<int MODE>
__device__ void eval_wave(float* __restrict__ px, float* __restrict__ py,
                          float* __restrict__ pz, float* __restrict__ cs,
                          const float* __restrict__ pos, const float* __restrict__ tc,
                          const float4* __restrict__ p4, int nv,
                          float& cf, float& cr, int wdir, float* __restrict__ out) {
  const int lane = threadIdx.x & 63;
  SegOut R;
  seg_pass(p4, lane, nv, pos[0], pos[1], pos[2], px, py, pz, R);

  // wave inclusive scan (DPP) of per-lane totals
  float inc = wave_incl_scan(R.run);
  float ex = inc - R.run;
  ((float4*)cs)[lane] = make_float4(ex, ex+R.cpre[0], ex+R.cpre[1], ex+R.cpre[2]);

  // Tot: segs >= nv-1 have len 0, so inclusive total == cs[nv-1]
  const float Tot = rlane_f(inc, 63);

  // coarse table -> SGPRs: co[k] = cs[16k+15] (lives on lane 4k+3)
  float cval = ex + R.cpre[2];
  float co[16];
  #pragma unroll
  for (int k=0;k<16;k++) co[k] = rfl_f(__shfl(cval, 4*k+3, 64));

  // global min of d2 via DPP, then first/last achieving lane via ballot
  float minv = wave_min_all(R.bdf);
  unsigned long long mf = __ballot(R.bdf == minv);
  unsigned long long ml = __ballot(R.bdl == minv);
  int lf = __builtin_ctzll(mf);
  int ll = 63 - __builtin_clzll(ml);
  int   jf = __builtin_amdgcn_readlane(R.bjf, lf);
  float tf = rlane_f(R.btf, lf);
  int   jl = __builtin_amdgcn_readlane(R.bjl, ll);
  float tl0 = rlane_f(R.btl, ll);

  // pre-issue tc loads for all passes (independent of the fence)
  constexpr int NPASS = (MODE==0)?3:2;
  float l_tc[NPASS];
  #pragma unroll
  for (int p=0;p<NPASS;p++){
    int task = p*64 + lane;
    int r = (MODE==0 && task>=TT) ? task-TT : task;
    int t = (r < TT) ? r : 0;
    l_tc[p] = tc[t];
  }

  lds_fence();  // cums/pts writes -> visible to cross-lane reads below

  float csjf = cs[jf], csjf1 = cs[jf+1];
  float csjl = cs[jl], csjl1 = cs[jl+1];
  float e0 = csjf + tf*(csjf1-csjf);
  float e1 = (Tot - csjl1) + (1.f-tl0)*(csjl1-csjl);

  const int jmaxv = nv-2;
  float accf=0.f, accr=0.f;
  #pragma unroll
  for (int p=0;p<NPASS;p++){
    int task = p*64 + lane;
    int dir, t; bool act;
    if (MODE==0){ act = task<2*TT; dir = task>=TT?1:0; t = dir ? task-TT : task; }
    else        { act = task<TT;   dir = wdir;         t = task; }
    float ts = (dir ? e1 : e0) + l_tc[p];
    ts = fminf(fmaxf(ts,0.f),Tot);
    int ia, ib; float tl;
    if (dir){
      float v = Tot - ts;
      int lb = count256<true>(cs, co, v);
      int j = nv-1-lb; j = j<0?0:(j>jmaxv?jmaxv:j);
      int l2 = nv-1-j;
      float base = Tot - cs[l2];
      tl = (ts-base)*frcp(fmaxf(cs[l2]-cs[l2-1], EPS_LEN));
      ia=l2; ib=l2-1;
    } else {
      int ub = count256<false>(cs, co, ts);
      int j = ub-1; j = j<0?0:(j>jmaxv?jmaxv:j);
      tl = (ts - cs[j])*frcp(fmaxf(cs[j+1]-cs[j], EPS_LEN));
      ia=j; ib=j+1;
    }
    tl = fminf(fmaxf(tl,0.f),1.f);
    float ax=px[ia], ay=py[ia], az=pz[ia];
    float bx=px[ib], by=py[ib], bz=pz[ib];
    float prx=ax+tl*(bx-ax), pry=ay+tl*(by-ay), prz=az+tl*(bz-az);
    if (MODE==1){
      if (act){ out[t*3+0]=prx; out[t*3+1]=pry; out[t*3+2]=prz; }
    } else if (act){
      float dx=pos[t*3+0]-prx, dy=pos[t*3+1]-pry, dz=pos[t*3+2]-prz;
      float dd=fsq(dx*dx+dy*dy+dz*dz);
      if (dir) accr+=dd; else accf+=dd;
    }
  }
  if (MODE==0){
    #pragma unroll
    for (int d=1;d<64;d<<=1){ accf+=__shfl_xor(accf,d,64); accr+=__shfl_xor(accr,d,64); }
    cf = accf; cr = accr;
  }
}

// K1: per-n trajectory cum arc length (one wave per n) + zero per-n counters
__global__ __launch_bounds__(256)
void traj_cs_kernel(const float* __restrict__ traj, float* __restrict__ tcs,
                    int* __restrict__ cnt) {
  const int wid = threadIdx.x>>6, lane = threadIdx.x&63;
  const int n = blockIdx.x*4 + wid;
  int g = blockIdx.x*256 + threadIdx.x;
  if (g < NN) __hip_atomic_store(&cnt[g], 0, __ATOMIC_RELAXED, __HIP_MEMORY_SCOPE_AGENT);
  const float* p = traj + (size_t)n*TT*3;
  float* o = tcs + (size_t)n*TT;
  float dx=p[(lane+1)*3+0]-p[lane*3+0];
  float dy=p[(lane+1)*3+1]-p[lane*3+1];
  float dz=p[(lane+1)*3+2]-p[lane*3+2];
  float sA = sqrtf(dx*dx+dy*dy+dz*dz);
  float incA = sA;
  #pragma unroll
  for (int d=1;d<64;d<<=1){ float ov=__shfl_up(incA,d,64); if(lane>=d) incA+=ov; }
  o[lane+1] = incA;
  float tot = __shfl(incA, 63, 64);
  float sB = 0.f;
  if (lane<15){
    int t = 64+lane;
    float ex=p[(t+1)*3+0]-p[t*3+0];
    float ey=p[(t+1)*3+1]-p[t*3+1];
    float ez=p[(t+1)*3+2]-p[t*3+2];
    sB = sqrtf(ex*ex+ey*ey+ez*ez);
  }
  float incB = sB;
  #pragma unroll
  for (int d=1;d<64;d<<=1){ float ov=__shfl_up(incB,d,64); if(lane>=d) incB+=ov; }
  if (lane<15) o[65+lane] = tot + incB;
  if (lane==0) o[0] = 0.f;
}

// K2 (fused): block = 4 waves = boundaries 4q..4q+3 of one n. Each wave
// computes both-direction costs; last block per n (atomic counter) runs the
// winner argmin + recompute in its wave 0. Output depends only on the 32
// final costs -> deterministic regardless of which block is last.
__global__ __launch_bounds__(256, 8)
void fused_kernel(const float* __restrict__ traj, const float* __restrict__ rp,
                  const void* __restrict__ mask, const float* __restrict__ tcs,
                  float* __restrict__ cost, int* __restrict__ cnt,
                  float* __restrict__ out) {
  __shared__ float s_px[4][NP], s_py[4][NP], s_pz[4][NP], s_cs[4][NP];
  __shared__ int s_last;
  const int wid = threadIdx.x>>6, lane = threadIdx.x&63;
  const int nb = blockIdx.x*4 + wid;
  const int n = nb >> 4;            // NBB == 16
  const float* pos = traj + (size_t)n*TT*3;
  const float* tc  = tcs  + (size_t)n*TT;

  int nvr = wave_nv(mask, (size_t)nb*NP, lane);
  float cf = INFINITY, cr = INFINITY;
  if (nvr >= 2){
    eval_wave<0>(s_px[wid],s_py[wid],s_pz[wid],s_cs[wid],
                 pos, tc, (const float4*)(rp+(size_t)nb*NP*3), nvr,
                 cf, cr, 0, nullptr);
  }
  if (lane==0){
    __hip_atomic_store(&cost[nb*2+0], cf, __ATOMIC_RELAXED, __HIP_MEMORY_SCOPE_AGENT);
    __hip_atomic_store(&cost[nb*2+1], cr, __ATOMIC_RELAXED, __HIP_MEMORY_SCOPE_AGENT);
  }
  __syncthreads();                  // all 8 cost stores of this block issued+drained
  if (threadIdx.x==0){
    __threadfence();                // release
    int old = __hip_atomic_fetch_add(&cnt[n], 1, __ATOMIC_ACQ_REL, __HIP_MEMORY_SCOPE_AGENT);
    s_last = (old==3) ? 1 : 0;
  }
  __syncthreads();
  if (!s_last || wid!=0) return;

  // ---- winner phase (wave 0 of last block for n) ----
  __threadfence();                  // acquire
  float bc = INFINITY;
  if (lane < NBB*2)
    bc = __hip_atomic_load(&cost[(size_t)n*NBB*2 + lane], __ATOMIC_RELAXED, __HIP_MEMORY_SCOPE_AGENT);
  int bi = (lane < NBB*2) ? lane : 64;
  #pragma unroll
  for (int d=1;d<64;d<<=1){
    float oc=__shfl_xor(bc,d,64); int oi=__shfl_xor(bi,d,64);
    if (oc<bc || (oc==bc && oi<bi)){bc=oc;bi=oi;}
  }
  float* o = out + (size_t)n*TT*3;
  if (bc == INFINITY){              // no valid candidate: passthrough
    if (lane < 60) ((float4*)o)[lane] = ((const float4*)pos)[lane];
    return;
  }
  int b = bi>>1, dir = bi&1;
  const size_t nbi = (size_t)n*NBB + b;
  int nv = wave_nv(mask, nbi*NP, lane);
  nv = max(nv, 2);
  float du0, du1;
  eval_wave<1>(s_px[0],s_py[0],s_pz[0],s_cs[0],
               pos, tc, (const float4*)(rp+nbi*NP*3), nv, du0, du1, dir, o);
}

extern "C" void kernel_launch(void* const* d_in, const int* in_sizes, int n_in,
                              void* d_out, int out_size, void* d_ws, size_t ws_size,
                              hipStream_t stream) {
  const float* traj = (const float*)d_in[0];
  const float* rp   = (const float*)d_in[1];
  const void*  mask = d_in[2];
  float* tcs  = (float*)d_ws;                    // NN*TT floats
  float* cost = tcs + (size_t)NN * TT;           // NN*NBB*2 floats
  int*   cnt  = (int*)(cost + (size_t)NN * NBB * 2);  // NN ints
  float* out  = (float*)d_out;

  hipLaunchKernelGGL(traj_cs_kernel, dim3(NN/4), dim3(256), 0, stream, traj, tcs, cnt);
  hipLaunchKernelGGL(fused_kernel, dim3(NN*NBB/4), dim3(256), 0, stream,
                     traj, rp, mask, tcs, cost, cnt, out);
}

// Round 8
// 35.658 us; speedup vs baseline: 6.8635x; 6.8635x over previous
//
#include <hip/hip_runtime.h>
#include <math.h>

#define NN 1024
#define NBB 16
#define NP 256
#define TT 80
#define EPS_LEN 1e-9f
#define EPS_DD 1e-12f

__device__ __forceinline__ float frcp(float x){ return __builtin_amdgcn_rcpf(x); }
__device__ __forceinline__ float fsq(float x){ return __builtin_amdgcn_sqrtf(x); }
__device__ __forceinline__ float rfl_f(float x){
  return __builtin_bit_cast(float, __builtin_amdgcn_readfirstlane(__builtin_bit_cast(int, x)));
}
__device__ __forceinline__ float rlane_f(float x, int l){
  return __builtin_bit_cast(float, __builtin_amdgcn_readlane(__builtin_bit_cast(int, x), l));
}

// ---- DPP wave64 primitives (canonical gfx9 sequence; validated R6) ----
template<int CTRL,int RM>
__device__ __forceinline__ float dpp_add(float v){
  int t = __builtin_amdgcn_update_dpp(0, __builtin_bit_cast(int, v), CTRL, RM, 0xf, true);
  return v + __builtin_bit_cast(float, t);
}
__device__ __forceinline__ float wave_incl_scan(float v){
  v = dpp_add<0x111,0xf>(v);   // row_shr:1
  v = dpp_add<0x112,0xf>(v);   // row_shr:2
  v = dpp_add<0x114,0xf>(v);   // row_shr:4
  v = dpp_add<0x118,0xf>(v);   // row_shr:8
  v = dpp_add<0x142,0xa>(v);   // row_bcast:15 -> rows 1,3
  v = dpp_add<0x143,0xc>(v);   // row_bcast:31 -> rows 2,3
  return v;
}
template<int CTRL,int RM>
__device__ __forceinline__ float dpp_min(float v){
  int t = __builtin_amdgcn_update_dpp(0x7f800000, __builtin_bit_cast(int,v), CTRL, RM, 0xf, false);
  return fminf(v, __builtin_bit_cast(float,t));
}
__device__ __forceinline__ float wave_min_all(float v){
  v=dpp_min<0x111,0xf>(v); v=dpp_min<0x112,0xf>(v);
  v=dpp_min<0x114,0xf>(v); v=dpp_min<0x118,0xf>(v);
  v=dpp_min<0x142,0xa>(v); v=dpp_min<0x143,0xc>(v);
  return rlane_f(v, 63);     // lane 63 holds global min
}

// Wave-synchronous LDS fence (LDS partitioned per wave; no __syncthreads).
__device__ __forceinline__ void lds_fence() {
  __builtin_amdgcn_wave_barrier();
  asm volatile("s_waitcnt lgkmcnt(0)" ::: "memory");
  __builtin_amdgcn_wave_barrier();
}

// n_valid, wave-wide. Mask layout auto-detect: byte[1] of buffer != 0 -> bool
// bytes (mask[0][0][1] true since lengths>=2); int32 layout -> that byte is 0.
__device__ __forceinline__ int wave_nv(const void* mask, size_t base, int lane) {
  bool as_byte = ((const unsigned char*)mask)[1] != 0;
  int nv = 0;
  if (as_byte) {
    uchar4 v = ((const uchar4*)((const unsigned char*)mask + base))[lane];
    nv += __popcll(__ballot(v.x != 0));
    nv += __popcll(__ballot(v.y != 0));
    nv += __popcll(__ballot(v.z != 0));
    nv += __popcll(__ballot(v.w != 0));
  } else {
    int4 v = ((const int4*)((const int*)mask + base))[lane];
    nv += __popcll(__ballot(v.x != 0));
    nv += __popcll(__ballot(v.y != 0));
    nv += __popcll(__ballot(v.z != 0));
    nv += __popcll(__ballot(v.w != 0));
  }
  return nv;
}

// Count of entries in cs[0..255] that are (< v) if STRICT else (<= v).
// co[16] are wave-uniform (SGPR) coarse values co[k] = cs[16k+15].
template<bool STRICT>
__device__ __forceinline__ int count256(const float* __restrict__ cs,
                                        const float* co, float v){
  int K = 0;
  #pragma unroll
  for (int k=0;k<16;k++) K += STRICT ? (co[k] < v) : (co[k] <= v);
  int base = (K < 16 ? K : 15) * 16;
  const float4* f4 = (const float4*)(cs + base);
  float4 c0=f4[0], c1=f4[1], c2=f4[2], c3=f4[3];
  int r;
  if (STRICT)
    r = (c0.x<v)+(c0.y<v)+(c0.z<v)+(c0.w<v)+(c1.x<v)+(c1.y<v)+(c1.z<v)+(c1.w<v)
      + (c2.x<v)+(c2.y<v)+(c2.z<v)+(c2.w<v)+(c3.x<v)+(c3.y<v)+(c3.z<v)+(c3.w<v);
  else
    r = (c0.x<=v)+(c0.y<=v)+(c0.z<=v)+(c0.w<=v)+(c1.x<=v)+(c1.y<=v)+(c1.z<=v)+(c1.w<=v)
      + (c2.x<=v)+(c2.y<=v)+(c2.z<=v)+(c2.w<=v)+(c3.x<=v)+(c3.y<=v)+(c3.z<=v)+(c3.w<=v);
  return (K >= 16) ? 256 : (base + r);
}

struct SegOut {
  float cpre[4];
  float run;
  float bdf, btf; int bjf;   // per-lane first-min (fwd)
  float bdl, btl; int bjl;   // per-lane last-min  (rev)
};

// Per-candidate segment pass. Lanes with j0 >= nv skip their point loads
// (those points are never read: interpolation indices stay <= nv-1).
__device__ __forceinline__ void seg_pass(const float4* __restrict__ p4, int lane, int nv,
                                         float p0x, float p0y, float p0z,
                                         float* __restrict__ px, float* __restrict__ py,
                                         float* __restrict__ pz, SegOut& R) {
  const int j0 = lane * 4;
  float4 A = make_float4(0.f,0.f,0.f,0.f), B = A, C = A;
  if (j0 < nv) { A = p4[lane*3+0]; B = p4[lane*3+1]; C = p4[lane*3+2]; }
  float x[5], y[5], z[5];
  x[0]=A.x; y[0]=A.y; z[0]=A.z;
  x[1]=A.w; y[1]=B.x; z[1]=B.y;
  x[2]=B.z; y[2]=B.w; z[2]=C.x;
  x[3]=C.y; y[3]=C.z; z[3]=C.w;
  x[4]=__shfl_down(x[0],1,64); y[4]=__shfl_down(y[0],1,64); z[4]=__shfl_down(z[0],1,64);
  ((float4*)px)[lane] = make_float4(x[0],x[1],x[2],x[3]);
  ((float4*)py)[lane] = make_float4(y[0],y[1],y[2],y[3]);
  ((float4*)pz)[lane] = make_float4(z[0],z[1],z[2],z[3]);
  float run = 0.f;
  R.bdf=INFINITY; R.btf=0.f; R.bjf=j0;
  R.bdl=INFINITY; R.btl=0.f; R.bjl=j0;
  #pragma unroll
  for (int k=0;k<4;k++){
    bool valid = (j0+k) < nv-1;
    float vx=x[k+1]-x[k], vy=y[k+1]-y[k], vz=z[k+1]-z[k];
    float n2 = vx*vx+vy*vy+vz*vz;
    float sl = valid ? fmaxf(fsq(n2), EPS_LEN) : 0.f;
    float t = ((p0x-x[k])*vx+(p0y-y[k])*vy+(p0z-z[k])*vz) * frcp(fmaxf(n2,EPS_DD));
    t = fminf(fmaxf(t,0.f),1.f);
    float qx=x[k]+t*vx, qy=y[k]+t*vy, qz=z[k]+t*vz;
    float dx=p0x-qx, dy=p0y-qy, dz=p0z-qz;
    float d2 = valid ? (dx*dx+dy*dy+dz*dz) : INFINITY;
    if (d2 <  R.bdf){R.bdf=d2; R.bjf=j0+k; R.btf=t;}
    if (d2 <= R.bdl){R.bdl=d2; R.bjl=j0+k; R.btl=t;}
    run += sl; R.cpre[k]=run;
  }
  R.run = run;
}

// One wave evaluates one (n,b), both directions fused.
// MODE 0: lane0 writes cost2[0]=fwd, cost2[1]=rev.  MODE 1: write dir=wdir proj.
template<int MODE>
__device__ void eval_wave(float* __restrict__ px, float* __restrict__ py,
                          float* __restrict__ pz, float* __restrict__ cs,
                          const float* __restrict__ pos, const float* __restrict__ tc,
                          const float4* __restrict__ p4, int nv,
                          float* __restrict__ cost2, int wdir, float* __restrict__ out) {
  const int lane = threadIdx.x & 63;
  SegOut R;
  seg_pass(p4, lane, nv, pos[0], pos[1], pos[2], px, py, pz, R);

  // wave inclusive scan (DPP) of per-lane totals
  float inc = wave_incl_scan(R.run);
  float ex = inc - R.run;
  ((float4*)cs)[lane] = make_float4(ex, ex+R.cpre[0], ex+R.cpre[1], ex+R.cpre[2]);

  // Tot: segs >= nv-1 have len 0, so inclusive total == cs[nv-1]
  const float Tot = rlane_f(inc, 63);

  // coarse table -> SGPRs: co[k] = cs[16k+15] (lives on lane 4k+3)
  float cval = ex + R.cpre[2];
  float co[16];
  #pragma unroll
  for (int k=0;k<16;k++) co[k] = rfl_f(__shfl(cval, 4*k+3, 64));

  // global min of d2 via DPP, then first/last achieving lane via ballot
  float minv = wave_min_all(R.bdf);
  unsigned long long mf = __ballot(R.bdf == minv);
  unsigned long long ml = __ballot(R.bdl == minv);
  int lf = __builtin_ctzll(mf);
  int ll = 63 - __builtin_clzll(ml);
  int   jf = __builtin_amdgcn_readlane(R.bjf, lf);
  float tf = rlane_f(R.btf, lf);
  int   jl = __builtin_amdgcn_readlane(R.bjl, ll);
  float tl0 = rlane_f(R.btl, ll);

  // pre-issue tc loads for all passes (independent of the fence)
  constexpr int NPASS = (MODE==0)?3:2;
  float l_tc[NPASS];
  #pragma unroll
  for (int p=0;p<NPASS;p++){
    int task = p*64 + lane;
    int r = (MODE==0 && task>=TT) ? task-TT : task;
    int t = (r < TT) ? r : 0;
    l_tc[p] = tc[t];
  }

  lds_fence();  // cums/pts writes -> visible to cross-lane reads below

  float csjf = cs[jf], csjf1 = cs[jf+1];
  float csjl = cs[jl], csjl1 = cs[jl+1];
  float e0 = csjf + tf*(csjf1-csjf);
  float e1 = (Tot - csjl1) + (1.f-tl0)*(csjl1-csjl);

  const int jmaxv = nv-2;
  float accf=0.f, accr=0.f;
  #pragma unroll
  for (int p=0;p<NPASS;p++){
    int task = p*64 + lane;
    int dir, t; bool act;
    if (MODE==0){ act = task<2*TT; dir = task>=TT?1:0; t = dir ? task-TT : task; }
    else        { act = task<TT;   dir = wdir;         t = task; }
    float ts = (dir ? e1 : e0) + l_tc[p];
    ts = fminf(fmaxf(ts,0.f),Tot);
    int ia, ib; float tl;
    if (dir){
      float v = Tot - ts;
      int lb = count256<true>(cs, co, v);
      int j = nv-1-lb; j = j<0?0:(j>jmaxv?jmaxv:j);
      int l2 = nv-1-j;
      float base = Tot - cs[l2];
      tl = (ts-base)*frcp(fmaxf(cs[l2]-cs[l2-1], EPS_LEN));
      ia=l2; ib=l2-1;
    } else {
      int ub = count256<false>(cs, co, ts);
      int j = ub-1; j = j<0?0:(j>jmaxv?jmaxv:j);
      tl = (ts - cs[j])*frcp(fmaxf(cs[j+1]-cs[j], EPS_LEN));
      ia=j; ib=j+1;
    }
    tl = fminf(fmaxf(tl,0.f),1.f);
    float ax=px[ia], ay=py[ia], az=pz[ia];
    float bx=px[ib], by=py[ib], bz=pz[ib];
    float prx=ax+tl*(bx-ax), pry=ay+tl*(by-ay), prz=az+tl*(bz-az);
    if (MODE==1){
      if (act){ out[t*3+0]=prx; out[t*3+1]=pry; out[t*3+2]=prz; }
    } else if (act){
      float dx=pos[t*3+0]-prx, dy=pos[t*3+1]-pry, dz=pos[t*3+2]-prz;
      float dd=fsq(dx*dx+dy*dy+dz*dz);
      if (dir) accr+=dd; else accf+=dd;
    }
  }
  if (MODE==0){
    #pragma unroll
    for (int d=1;d<64;d<<=1){ accf+=__shfl_xor(accf,d,64); accr+=__shfl_xor(accr,d,64); }
    if (lane==0){ cost2[0]=accf; cost2[1]=accr; }
  }
}

// K1: per-n trajectory cum arc length, one wave per n
__global__ __launch_bounds__(256)
void traj_cs_kernel(const float* __restrict__ traj, float* __restrict__ tcs) {
  const int wid = threadIdx.x>>6, lane = threadIdx.x&63;
  const int n = blockIdx.x*4 + wid;
  const float* p = traj + (size_t)n*TT*3;
  float* o = tcs + (size_t)n*TT;
  float dx=p[(lane+1)*3+0]-p[lane*3+0];
  float dy=p[(lane+1)*3+1]-p[lane*3+1];
  float dz=p[(lane+1)*3+2]-p[lane*3+2];
  float sA = sqrtf(dx*dx+dy*dy+dz*dz);
  float incA = sA;
  #pragma unroll
  for (int d=1;d<64;d<<=1){ float ov=__shfl_up(incA,d,64); if(lane>=d) incA+=ov; }
  o[lane+1] = incA;
  float tot = __shfl(incA, 63, 64);
  float sB = 0.f;
  if (lane<15){
    int t = 64+lane;
    float ex=p[(t+1)*3+0]-p[t*3+0];
    float ey=p[(t+1)*3+1]-p[t*3+1];
    float ez=p[(t+1)*3+2]-p[t*3+2];
    sB = sqrtf(ex*ex+ey*ey+ez*ez);
  }
  float incB = sB;
  #pragma unroll
  for (int d=1;d<64;d<<=1){ float ov=__shfl_up(incB,d,64); if(lane>=d) incB+=ov; }
  if (lane<15) o[65+lane] = tot + incB;
  if (lane==0) o[0] = 0.f;
}

// K2: one wave per (n,b) -> both-direction costs.
__global__ __launch_bounds__(256, 8)
void fused_cost_kernel(const float* __restrict__ traj, const float* __restrict__ rp,
                       const void* __restrict__ mask, const float* __restrict__ tcs,
                       float* __restrict__ cost) {
  __shared__ float s_px[4][NP], s_py[4][NP], s_pz[4][NP], s_cs[4][NP];
  const int wid = threadIdx.x>>6, lane = threadIdx.x&63;
  const int nb = blockIdx.x*4 + wid;
  const int n = nb / NBB;
  int nvr = wave_nv(mask, (size_t)nb*NP, lane);
  if (nvr < 2){
    if (lane==0){ cost[nb*2+0]=INFINITY; cost[nb*2+1]=INFINITY; }
    return;
  }
  eval_wave<0>(s_px[wid],s_py[wid],s_pz[wid],s_cs[wid],
               traj+(size_t)n*TT*3, tcs+(size_t)n*TT,
               (const float4*)(rp+(size_t)nb*NP*3), nvr,
               cost+(size_t)nb*2, 0, nullptr);
}

// K3: one wave per n -> argmin over 32 candidates, recompute winner, write out
__global__ __launch_bounds__(256)
void winner_kernel(const float* __restrict__ traj, const float* __restrict__ rp,
                   const void* __restrict__ mask, const float* __restrict__ tcs,
                   const float* __restrict__ cost, float* __restrict__ out) {
  __shared__ float s_px[4][NP], s_py[4][NP], s_pz[4][NP], s_cs[4][NP];
  const int wid = threadIdx.x>>6, lane = threadIdx.x&63;
  const int n = blockIdx.x*4 + wid;
  const float* c = cost + (size_t)n*NBB*2;
  float bc = (lane<NBB*2) ? c[lane] : INFINITY;
  int bi = (lane<NBB*2) ? lane : 64;
  #pragma unroll
  for (int d=1;d<64;d<<=1){
    float oc=__shfl_xor(bc,d,64); int oi=__shfl_xor(bi,d,64);
    if (oc<bc || (oc==bc && oi<bi)){bc=oc;bi=oi;}
  }
  const float* pos = traj + (size_t)n*TT*3;
  float* o = out + (size_t)n*TT*3;
  if (bc == INFINITY){  // no valid candidate: passthrough
    if (lane < 60) ((float4*)o)[lane] = ((const float4*)pos)[lane];
    return;
  }
  int b = bi>>1, dir = bi&1;
  const size_t nbi = (size_t)n*NBB + b;
  int nv = wave_nv(mask, nbi*NP, lane);
  nv = max(nv, 2);
  eval_wave<1>(s_px[wid],s_py[wid],s_pz[wid],s_cs[wid],
               pos, tcs+(size_t)n*TT,
               (const float4*)(rp+nbi*NP*3), nv, nullptr, dir, o);
}

extern "C" void kernel_launch(void* const* d_in, const int* in_sizes, int n_in,
                              void* d_out, int out_size, void* d_ws, size_t ws_size,
                              hipStream_t stream) {
  const float* traj = (const float*)d_in[0];
  const float* rp   = (const float*)d_in[1];
  const void*  mask = d_in[2];
  float* tcs  = (float*)d_ws;                    // NN*TT floats
  float* cost = tcs + (size_t)NN * TT;           // NN*NBB*2 floats
  float* out  = (float*)d_out;

  hipLaunchKernelGGL(traj_cs_kernel, dim3(NN/4), dim3(256), 0, stream, traj, tcs);
  hipLaunchKernelGGL(fused_cost_kernel, dim3(NN*NBB/4), dim3(256), 0, stream,
                     traj, rp, mask, tcs, cost);
  hipLaunchKernelGGL(winner_kernel, dim3(NN/4), dim3(256), 0, stream,
                     traj, rp, mask, tcs, cost, out);
}

// Round 9
// 34.912 us; speedup vs baseline: 7.0103x; 1.0214x over previous
//
#include <hip/hip_runtime.h>
#include <math.h>

#define NN 1024
#define NBB 16
#define NP 256
#define TT 80
#define EPS_LEN 1e-9f
#define EPS_DD 1e-12f

__device__ __forceinline__ float frcp(float x){ return __builtin_amdgcn_rcpf(x); }
__device__ __forceinline__ float fsq(float x){ return __builtin_amdgcn_sqrtf(x); }
__device__ __forceinline__ float rlane_f(float x, int l){
  return __builtin_bit_cast(float, __builtin_amdgcn_readlane(__builtin_bit_cast(int, x), l));
}

// ---- DPP wave64 primitives (canonical gfx9 sequence; validated R6/R7) ----
template<int CTRL,int RM>
__device__ __forceinline__ float dpp_add(float v){
  int t = __builtin_amdgcn_update_dpp(0, __builtin_bit_cast(int, v), CTRL, RM, 0xf, true);
  return v + __builtin_bit_cast(float, t);
}
__device__ __forceinline__ float wave_incl_scan(float v){
  v = dpp_add<0x111,0xf>(v);   // row_shr:1
  v = dpp_add<0x112,0xf>(v);   // row_shr:2
  v = dpp_add<0x114,0xf>(v);   // row_shr:4
  v = dpp_add<0x118,0xf>(v);   // row_shr:8
  v = dpp_add<0x142,0xa>(v);   // row_bcast:15 -> rows 1,3
  v = dpp_add<0x143,0xc>(v);   // row_bcast:31 -> rows 2,3
  return v;
}
__device__ __forceinline__ float wave_sum(float v){ return rlane_f(wave_incl_scan(v), 63); }
template<int CTRL,int RM>
__device__ __forceinline__ float dpp_min(float v){
  int t = __builtin_amdgcn_update_dpp(0x7f800000, __builtin_bit_cast(int,v), CTRL, RM, 0xf, false);
  return fminf(v, __builtin_bit_cast(float,t));
}
__device__ __forceinline__ float wave_min_all(float v){
  v=dpp_min<0x111,0xf>(v); v=dpp_min<0x112,0xf>(v);
  v=dpp_min<0x114,0xf>(v); v=dpp_min<0x118,0xf>(v);
  v=dpp_min<0x142,0xa>(v); v=dpp_min<0x143,0xc>(v);
  return rlane_f(v, 63);
}

// Wave-synchronous LDS fence (LDS partitioned per wave; no __syncthreads).
__device__ __forceinline__ void lds_fence() {
  __builtin_amdgcn_wave_barrier();
  asm volatile("s_waitcnt lgkmcnt(0)" ::: "memory");
  __builtin_amdgcn_wave_barrier();
}

// n_valid, wave-wide. Mask layout auto-detect: byte[1] of buffer != 0 -> bool
// bytes (mask[0][0][1] true since lengths>=2); int32 layout -> that byte is 0.
__device__ __forceinline__ int wave_nv(const void* mask, size_t base, int lane) {
  bool as_byte = ((const unsigned char*)mask)[1] != 0;
  int nv = 0;
  if (as_byte) {
    uchar4 v = ((const uchar4*)((const unsigned char*)mask + base))[lane];
    nv += __popcll(__ballot(v.x != 0));
    nv += __popcll(__ballot(v.y != 0));
    nv += __popcll(__ballot(v.z != 0));
    nv += __popcll(__ballot(v.w != 0));
  } else {
    int4 v = ((const int4*)((const int*)mask + base))[lane];
    nv += __popcll(__ballot(v.x != 0));
    nv += __popcll(__ballot(v.y != 0));
    nv += __popcll(__ballot(v.z != 0));
    nv += __popcll(__ballot(v.w != 0));
  }
  return nv;
}

// Count of entries in cs[0..255] that are (< v) if STRICT else (<= v).
// co[16] are wave-uniform coarse values co[k] = cs[16k+15].
template<bool STRICT>
__device__ __forceinline__ int count256(const float* __restrict__ cs,
                                        const float* co, float v){
  int K = 0;
  #pragma unroll
  for (int k=0;k<16;k++) K += STRICT ? (co[k] < v) : (co[k] <= v);
  int base = (K < 16 ? K : 15) * 16;
  const float4* f4 = (const float4*)(cs + base);
  float4 c0=f4[0], c1=f4[1], c2=f4[2], c3=f4[3];
  int r;
  if (STRICT)
    r = (c0.x<v)+(c0.y<v)+(c0.z<v)+(c0.w<v)+(c1.x<v)+(c1.y<v)+(c1.z<v)+(c1.w<v)
      + (c2.x<v)+(c2.y<v)+(c2.z<v)+(c2.w<v)+(c3.x<v)+(c3.y<v)+(c3.z<v)+(c3.w<v);
  else
    r = (c0.x<=v)+(c0.y<=v)+(c0.z<=v)+(c0.w<=v)+(c1.x<=v)+(c1.y<=v)+(c1.z<=v)+(c1.w<=v)
      + (c2.x<=v)+(c2.y<=v)+(c2.z<=v)+(c2.w<=v)+(c3.x<=v)+(c3.y<=v)+(c3.z<=v)+(c3.w<=v);
  return (K >= 16) ? 256 : (base + r);
}

struct SegOut {
  float cpre[4];
  float run;
  float bdf, btf; int bjf;   // per-lane first-min (fwd)
  float bdl, btl; int bjl;   // per-lane last-min  (rev)
};

// Per-candidate segment pass. pts = packed [256][3] floats in LDS.
// Lanes with j0 >= nv skip loads (those entries are never read downstream).
template<bool NEEDMIN>
__device__ __forceinline__ void seg_pass(const float4* __restrict__ p4, int lane, int nv,
                                         float p0x, float p0y, float p0z,
                                         float* __restrict__ pts, SegOut& R) {
  const int j0 = lane * 4;
  float4 A = make_float4(0.f,0.f,0.f,0.f), B = A, C = A;
  if (j0 < nv) { A = p4[lane*3+0]; B = p4[lane*3+1]; C = p4[lane*3+2]; }
  float x[5], y[5], z[5];
  x[0]=A.x; y[0]=A.y; z[0]=A.z;
  x[1]=A.w; y[1]=B.x; z[1]=B.y;
  x[2]=B.z; y[2]=B.w; z[2]=C.x;
  x[3]=C.y; y[3]=C.z; z[3]=C.w;
  x[4]=__shfl_down(x[0],1,64); y[4]=__shfl_down(y[0],1,64); z[4]=__shfl_down(z[0],1,64);
  // packed write: 48B contiguous per lane, 3 x b128
  ((float4*)pts)[lane*3+0] = make_float4(x[0],y[0],z[0],x[1]);
  ((float4*)pts)[lane*3+1] = make_float4(y[1],z[1],x[2],y[2]);
  ((float4*)pts)[lane*3+2] = make_float4(z[2],x[3],y[3],z[3]);
  float run = 0.f;
  R.bdf=INFINITY; R.btf=0.f; R.bjf=j0;
  R.bdl=INFINITY; R.btl=0.f; R.bjl=j0;
  #pragma unroll
  for (int k=0;k<4;k++){
    bool valid = (j0+k) < nv-1;
    float vx=x[k+1]-x[k], vy=y[k+1]-y[k], vz=z[k+1]-z[k];
    float n2 = vx*vx+vy*vy+vz*vz;
    float sl = valid ? fmaxf(fsq(n2), EPS_LEN) : 0.f;
    if (NEEDMIN){
      float t = ((p0x-x[k])*vx+(p0y-y[k])*vy+(p0z-z[k])*vz) * frcp(fmaxf(n2,EPS_DD));
      t = fminf(fmaxf(t,0.f),1.f);
      float qx=x[k]+t*vx, qy=y[k]+t*vy, qz=z[k]+t*vz;
      float dx=p0x-qx, dy=p0y-qy, dz=p0z-qz;
      float d2 = valid ? (dx*dx+dy*dy+dz*dz) : INFINITY;
      if (d2 <  R.bdf){R.bdf=d2; R.bjf=j0+k; R.btf=t;}
      if (d2 <= R.bdl){R.bdl=d2; R.bjl=j0+k; R.btl=t;}
    }
    run += sl; R.cpre[k]=run;
  }
  R.run = run;
}

// cs[idx] and cs[idx+1] reconstructed from scan registers (uniform idx).
__device__ __forceinline__ void cs_pair_from_regs(int idx, float ex, const SegOut& R,
                                                  float& c0, float& c1){
  int o = idx >> 2, r = idx & 3;
  float a0 = (r==0)?0.f : (r==1)?R.cpre[0] : (r==2)?R.cpre[1] : R.cpre[2];
  float a1 = (r==0)?R.cpre[0] : (r==1)?R.cpre[1] : (r==2)?R.cpre[2] : R.run;
  c0 = rlane_f(ex + a0, o);
  c1 = rlane_f(ex + a1, o);
}

// Shared timestep interpolation. Returns proj (prx,pry,prz) for target ts.
__device__ __forceinline__ void interp_at(const float* __restrict__ pts,
                                          const float* __restrict__ cs,
                                          const float* co, float Tot, int nv, int jmaxv,
                                          int dir, float ts,
                                          float& prx, float& pry, float& prz){
  int ia, ib; float tl;
  if (dir){
    float v = Tot - ts;
    int lb = count256<true>(cs, co, v);
    int j = nv-1-lb; j = j<0?0:(j>jmaxv?jmaxv:j);
    int l2 = nv-1-j;
    float base = Tot - cs[l2];
    tl = (ts-base)*frcp(fmaxf(cs[l2]-cs[l2-1], EPS_LEN));
    ia=l2; ib=l2-1;
  } else {
    int ub = count256<false>(cs, co, ts);
    int j = ub-1; j = j<0?0:(j>jmaxv?jmaxv:j);
    tl = (ts - cs[j])*frcp(fmaxf(cs[j+1]-cs[j], EPS_LEN));
    ia=j; ib=j+1;
  }
  tl = fminf(fmaxf(tl,0.f),1.f);
  float3 PA = *(const float3*)(pts + ia*3);
  float3 PB = *(const float3*)(pts + ib*3);
  prx = PA.x + tl*(PB.x-PA.x);
  pry = PA.y + tl*(PB.y-PA.y);
  prz = PA.z + tl*(PB.z-PA.z);
}

// K2 worker: one wave, one (n,b), both directions. Writes cost2 and ent2.
__device__ void eval_cost_wave(float* __restrict__ pts, float* __restrict__ cs,
                               const float* __restrict__ pos, const float* __restrict__ tc,
                               const float4* __restrict__ p4, int nv,
                               float* __restrict__ cost2, float2* __restrict__ ent2){
  const int lane = threadIdx.x & 63;
  // early independent loads
  float l_tc[3];
  #pragma unroll
  for (int p=0;p<3;p++){
    int task = p*64 + lane;
    int r = task>=TT ? task-TT : task;
    int t = (r<TT) ? r : 0;
    l_tc[p] = tc[t];
  }
  SegOut R;
  seg_pass<true>(p4, lane, nv, pos[0], pos[1], pos[2], pts, R);

  float inc = wave_incl_scan(R.run);
  float ex = inc - R.run;
  ((float4*)cs)[lane] = make_float4(ex, ex+R.cpre[0], ex+R.cpre[1], ex+R.cpre[2]);
  const float Tot = rlane_f(inc, 63);

  // coarse table via v_readlane (zero DS): co[k] = cs[16k+15] on lane 4k+3
  float cval = ex + R.cpre[2];
  float co[16];
  #pragma unroll
  for (int k=0;k<16;k++) co[k] = rlane_f(cval, 4*k+3);

  // global min of d2 via DPP, then first/last achieving lane via ballot
  float minv = wave_min_all(R.bdf);
  unsigned long long mf = __ballot(R.bdf == minv);
  unsigned long long ml = __ballot(R.bdl == minv);
  int lf = __builtin_ctzll(mf);
  int ll = 63 - __builtin_clzll(ml);
  int   jf = __builtin_amdgcn_readlane(R.bjf, lf);
  float tf = rlane_f(R.btf, lf);
  int   jl = __builtin_amdgcn_readlane(R.bjl, ll);
  float tl0 = rlane_f(R.btl, ll);

  // entry points from registers (pre-fence, off the LDS critical path)
  float cjf, cjf1, cjl, cjl1;
  cs_pair_from_regs(jf, ex, R, cjf, cjf1);
  cs_pair_from_regs(jl, ex, R, cjl, cjl1);
  float e0 = cjf + tf*(cjf1-cjf);
  float e1 = (Tot - cjl1) + (1.f-tl0)*(cjl1-cjl);

  lds_fence();  // pts/cs writes -> visible to cross-lane reads below

  const int jmaxv = nv-2;
  float accf=0.f, accr=0.f;
  #pragma unroll
  for (int p=0;p<3;p++){
    int task = p*64 + lane;
    bool act = task < 2*TT;
    int dir = task>=TT ? 1 : 0;
    int t = dir ? task-TT : task;
    float ts = (dir ? e1 : e0) + l_tc[p];
    ts = fminf(fmaxf(ts,0.f),Tot);
    float prx,pry,prz;
    interp_at(pts, cs, co, Tot, nv, jmaxv, dir, ts, prx,pry,prz);
    if (act){
      float dx=pos[t*3+0]-prx, dy=pos[t*3+1]-pry, dz=pos[t*3+2]-prz;
      float dd=fsq(dx*dx+dy*dy+dz*dz);
      if (dir) accr+=dd; else accf+=dd;
    }
  }
  float cf = wave_sum(accf), cr = wave_sum(accr);
  if (lane==0){
    cost2[0]=cf; cost2[1]=cr;
    *ent2 = make_float2(e0, e1);
  }
}

// K3 worker: winner recompute without argmin (entry given), write projections.
__device__ void eval_proj_wave(float* __restrict__ pts, float* __restrict__ cs,
                               const float* __restrict__ tc,
                               const float4* __restrict__ p4, int nv,
                               int wdir, float entry, float* __restrict__ out){
  const int lane = threadIdx.x & 63;
  float l_tc[2];
  #pragma unroll
  for (int p=0;p<2;p++){
    int t = p*64 + lane;
    l_tc[p] = tc[(t<TT)?t:0];
  }
  SegOut R;
  seg_pass<false>(p4, lane, nv, 0.f,0.f,0.f, pts, R);
  float inc = wave_incl_scan(R.run);
  float ex = inc - R.run;
  ((float4*)cs)[lane] = make_float4(ex, ex+R.cpre[0], ex+R.cpre[1], ex+R.cpre[2]);
  const float Tot = rlane_f(inc, 63);
  float cval = ex + R.cpre[2];
  float co[16];
  #pragma unroll
  for (int k=0;k<16;k++) co[k] = rlane_f(cval, 4*k+3);
  lds_fence();
  const int jmaxv = nv-2;
  #pragma unroll
  for (int p=0;p<2;p++){
    int t = p*64 + lane;
    float ts = entry + l_tc[p];
    ts = fminf(fmaxf(ts,0.f),Tot);
    float prx,pry,prz;
    interp_at(pts, cs, co, Tot, nv, jmaxv, wdir, ts, prx,pry,prz);
    if (t < TT){ out[t*3+0]=prx; out[t*3+1]=pry; out[t*3+2]=prz; }
  }
}

// K1: per-n trajectory cum arc length, one wave per n
__global__ __launch_bounds__(256)
void traj_cs_kernel(const float* __restrict__ traj, float* __restrict__ tcs) {
  const int wid = threadIdx.x>>6, lane = threadIdx.x&63;
  const int n = blockIdx.x*4 + wid;
  const float* p = traj + (size_t)n*TT*3;
  float* o = tcs + (size_t)n*TT;
  float dx=p[(lane+1)*3+0]-p[lane*3+0];
  float dy=p[(lane+1)*3+1]-p[lane*3+1];
  float dz=p[(lane+1)*3+2]-p[lane*3+2];
  float sA = sqrtf(dx*dx+dy*dy+dz*dz);
  float incA = sA;
  #pragma unroll
  for (int d=1;d<64;d<<=1){ float ov=__shfl_up(incA,d,64); if(lane>=d) incA+=ov; }
  o[lane+1] = incA;
  float tot = __shfl(incA, 63, 64);
  float sB = 0.f;
  if (lane<15){
    int t = 64+lane;
    float ex=p[(t+1)*3+0]-p[t*3+0];
    float ey=p[(t+1)*3+1]-p[t*3+1];
    float ez=p[(t+1)*3+2]-p[t*3+2];
    sB = sqrtf(ex*ex+ey*ey+ez*ez);
  }
  float incB = sB;
  #pragma unroll
  for (int d=1;d<64;d<<=1){ float ov=__shfl_up(incB,d,64); if(lane>=d) incB+=ov; }
  if (lane<15) o[65+lane] = tot + incB;
  if (lane==0) o[0] = 0.f;
}

// K2: one wave per (n,b) -> both-direction costs + entry points.
__global__ __launch_bounds__(256, 8)
void fused_cost_kernel(const float* __restrict__ traj, const float* __restrict__ rp,
                       const void* __restrict__ mask, const float* __restrict__ tcs,
                       float* __restrict__ cost, float2* __restrict__ ent) {
  __shared__ float s_pts[4][NP*3], s_cs[4][NP];
  const int wid = threadIdx.x>>6, lane = threadIdx.x&63;
  const int nb = blockIdx.x*4 + wid;
  const int n = nb / NBB;
  int nvr = wave_nv(mask, (size_t)nb*NP, lane);
  if (nvr < 2){
    if (lane==0){ cost[nb*2+0]=INFINITY; cost[nb*2+1]=INFINITY; }
    return;
  }
  eval_cost_wave(s_pts[wid], s_cs[wid],
                 traj+(size_t)n*TT*3, tcs+(size_t)n*TT,
                 (const float4*)(rp+(size_t)nb*NP*3), nvr,
                 cost+(size_t)nb*2, ent+nb);
}

// K3: one wave per n -> argmin over 32 candidates, recompute winner, write out
__global__ __launch_bounds__(256)
void winner_kernel(const float* __restrict__ traj, const float* __restrict__ rp,
                   const void* __restrict__ mask, const float* __restrict__ tcs,
                   const float* __restrict__ cost, const float2* __restrict__ ent,
                   float* __restrict__ out) {
  __shared__ float s_pts[4][NP*3], s_cs[4][NP];
  const int wid = threadIdx.x>>6, lane = threadIdx.x&63;
  const int n = blockIdx.x*4 + wid;
  const float* c = cost + (size_t)n*NBB*2;
  float bc = (lane<NBB*2) ? c[lane] : INFINITY;
  int bi = (lane<NBB*2) ? lane : 64;
  #pragma unroll
  for (int d=1;d<64;d<<=1){
    float oc=__shfl_xor(bc,d,64); int oi=__shfl_xor(bi,d,64);
    if (oc<bc || (oc==bc && oi<bi)){bc=oc;bi=oi;}
  }
  const float* pos = traj + (size_t)n*TT*3;
  float* o = out + (size_t)n*TT*3;
  if (bc == INFINITY){  // no valid candidate: passthrough
    if (lane < 60) ((float4*)o)[lane] = ((const float4*)pos)[lane];
    return;
  }
  int b = bi>>1, dir = bi&1;
  const size_t nbi = (size_t)n*NBB + b;
  float2 eW = ent[nbi];
  float entry = dir ? eW.y : eW.x;
  int nv = wave_nv(mask, nbi*NP, lane);
  nv = max(nv, 2);
  eval_proj_wave(s_pts[wid], s_cs[wid], tcs+(size_t)n*TT,
                 (const float4*)(rp+nbi*NP*3), nv, dir, entry, o);
}

extern "C" void kernel_launch(void* const* d_in, const int* in_sizes, int n_in,
                              void* d_out, int out_size, void* d_ws, size_t ws_size,
                              hipStream_t stream) {
  const float* traj = (const float*)d_in[0];
  const float* rp   = (const float*)d_in[1];
  const void*  mask = d_in[2];
  float* tcs  = (float*)d_ws;                        // NN*TT floats
  float* cost = tcs + (size_t)NN * TT;               // NN*NBB*2 floats
  float2* ent = (float2*)(cost + (size_t)NN*NBB*2);  // NN*NBB float2
  float* out  = (float*)d_out;

  hipLaunchKernelGGL(traj_cs_kernel, dim3(NN/4), dim3(256), 0, stream, traj, tcs);
  hipLaunchKernelGGL(fused_cost_kernel, dim3(NN*NBB/4), dim3(256), 0, stream,
                     traj, rp, mask, tcs, cost, ent);
  hipLaunchKernelGGL(winner_kernel, dim3(NN/4), dim3(256), 0, stream,
                     traj, rp, mask, tcs, cost, ent, out);
}

// Round 10
// 31.939 us; speedup vs baseline: 7.6629x; 1.0931x over previous
//
#include <hip/hip_runtime.h>
#include <math.h>

#define NN 1024
#define NBB 16
#define NP 256
#define TT 80
#define EPS_LEN 1e-9f
#define EPS_DD 1e-12f

__device__ __forceinline__ float frcp(float x){ return __builtin_amdgcn_rcpf(x); }
__device__ __forceinline__ float fsq(float x){ return __builtin_amdgcn_sqrtf(x); }
__device__ __forceinline__ float rlane_f(float x, int l){
  return __builtin_bit_cast(float, __builtin_amdgcn_readlane(__builtin_bit_cast(int, x), l));
}
// count(c <= v) == count(c < bump(v)) exactly for nonneg floats
__device__ __forceinline__ float bump(float v){
  return __builtin_bit_cast(float, __builtin_bit_cast(int, v) + 1);
}

// ---- DPP wave64 primitives (canonical gfx9 sequence; validated R6-R8) ----
template<int CTRL,int RM>
__device__ __forceinline__ float dpp_add(float v){
  int t = __builtin_amdgcn_update_dpp(0, __builtin_bit_cast(int, v), CTRL, RM, 0xf, true);
  return v + __builtin_bit_cast(float, t);
}
__device__ __forceinline__ float wave_incl_scan(float v){
  v = dpp_add<0x111,0xf>(v);   // row_shr:1
  v = dpp_add<0x112,0xf>(v);   // row_shr:2
  v = dpp_add<0x114,0xf>(v);   // row_shr:4
  v = dpp_add<0x118,0xf>(v);   // row_shr:8
  v = dpp_add<0x142,0xa>(v);   // row_bcast:15 -> rows 1,3
  v = dpp_add<0x143,0xc>(v);   // row_bcast:31 -> rows 2,3
  return v;
}
__device__ __forceinline__ float wave_sum(float v){ return rlane_f(wave_incl_scan(v), 63); }
template<int CTRL,int RM>
__device__ __forceinline__ float dpp_min(float v){
  int t = __builtin_amdgcn_update_dpp(0x7f800000, __builtin_bit_cast(int,v), CTRL, RM, 0xf, false);
  return fminf(v, __builtin_bit_cast(float,t));
}
__device__ __forceinline__ float wave_min_all(float v){
  v=dpp_min<0x111,0xf>(v); v=dpp_min<0x112,0xf>(v);
  v=dpp_min<0x114,0xf>(v); v=dpp_min<0x118,0xf>(v);
  v=dpp_min<0x142,0xa>(v); v=dpp_min<0x143,0xc>(v);
  return rlane_f(v, 63);
}

// Wave-synchronous LDS fence (LDS partitioned per wave; no __syncthreads).
__device__ __forceinline__ void lds_fence() {
  __builtin_amdgcn_wave_barrier();
  asm volatile("s_waitcnt lgkmcnt(0)" ::: "memory");
  __builtin_amdgcn_wave_barrier();
}

// n_valid, wave-wide. Mask layout auto-detect: byte[1] of buffer != 0 -> bool
// bytes (mask[0][0][1] true since lengths>=2); int32 layout -> that byte is 0.
__device__ __forceinline__ int wave_nv(const void* mask, size_t base, int lane) {
  bool as_byte = ((const unsigned char*)mask)[1] != 0;
  int nv = 0;
  if (as_byte) {
    uchar4 v = ((const uchar4*)((const unsigned char*)mask + base))[lane];
    nv += __popcll(__ballot(v.x != 0));
    nv += __popcll(__ballot(v.y != 0));
    nv += __popcll(__ballot(v.z != 0));
    nv += __popcll(__ballot(v.w != 0));
  } else {
    int4 v = ((const int4*)((const int*)mask + base))[lane];
    nv += __popcll(__ballot(v.x != 0));
    nv += __popcll(__ballot(v.y != 0));
    nv += __popcll(__ballot(v.z != 0));
    nv += __popcll(__ballot(v.w != 0));
  }
  return nv;
}

// Count of entries in cs[0..255] strictly < v. co[16] wave-uniform (SGPR),
// co[k] = cs[16k+15]. Non-strict counts use bump(v).
__device__ __forceinline__ int count256s(const float* __restrict__ cs,
                                         const float* co, float v){
  int K = 0;
  #pragma unroll
  for (int k=0;k<16;k++) K += (co[k] < v);
  int base = (K < 16 ? K : 15) * 16;
  const float4* f4 = (const float4*)(cs + base);
  float4 c0=f4[0], c1=f4[1], c2=f4[2], c3=f4[3];
  int r = (c0.x<v)+(c0.y<v)+(c0.z<v)+(c0.w<v)+(c1.x<v)+(c1.y<v)+(c1.z<v)+(c1.w<v)
        + (c2.x<v)+(c2.y<v)+(c2.z<v)+(c2.w<v)+(c3.x<v)+(c3.y<v)+(c3.z<v)+(c3.w<v);
  return (K >= 16) ? 256 : (base + r);
}

struct SegOut {
  float cpre[4];
  float run;
  float bdf, btf; int bjf;   // per-lane first-min (fwd)
  float bdl, btl; int bjl;   // per-lane last-min  (rev)
};

// Segment pass on preloaded point regs; stages packed [256][3] pts to LDS.
template<bool NEEDMIN>
__device__ __forceinline__ void seg_pass(float4 A, float4 B, float4 C,
                                         int lane, int nv,
                                         float p0x, float p0y, float p0z,
                                         float* __restrict__ pts, SegOut& R) {
  const int j0 = lane * 4;
  float x[5], y[5], z[5];
  x[0]=A.x; y[0]=A.y; z[0]=A.z;
  x[1]=A.w; y[1]=B.x; z[1]=B.y;
  x[2]=B.z; y[2]=B.w; z[2]=C.x;
  x[3]=C.y; y[3]=C.z; z[3]=C.w;
  x[4]=__shfl_down(x[0],1,64); y[4]=__shfl_down(y[0],1,64); z[4]=__shfl_down(z[0],1,64);
  ((float4*)pts)[lane*3+0] = make_float4(x[0],y[0],z[0],x[1]);
  ((float4*)pts)[lane*3+1] = make_float4(y[1],z[1],x[2],y[2]);
  ((float4*)pts)[lane*3+2] = make_float4(z[2],x[3],y[3],z[3]);
  float run = 0.f;
  R.bdf=INFINITY; R.btf=0.f; R.bjf=j0;
  R.bdl=INFINITY; R.btl=0.f; R.bjl=j0;
  #pragma unroll
  for (int k=0;k<4;k++){
    bool valid = (j0+k) < nv-1;
    float vx=x[k+1]-x[k], vy=y[k+1]-y[k], vz=z[k+1]-z[k];
    float n2 = vx*vx+vy*vy+vz*vz;
    float sl = valid ? fmaxf(fsq(n2), EPS_LEN) : 0.f;
    if (NEEDMIN){
      float t = ((p0x-x[k])*vx+(p0y-y[k])*vy+(p0z-z[k])*vz) * frcp(fmaxf(n2,EPS_DD));
      t = fminf(fmaxf(t,0.f),1.f);
      float qx=x[k]+t*vx, qy=y[k]+t*vy, qz=z[k]+t*vz;
      float dx=p0x-qx, dy=p0y-qy, dz=p0z-qz;
      float d2 = valid ? (dx*dx+dy*dy+dz*dz) : INFINITY;
      if (d2 <  R.bdf){R.bdf=d2; R.bjf=j0+k; R.btf=t;}
      if (d2 <= R.bdl){R.bdl=d2; R.bjl=j0+k; R.btl=t;}
    }
    run += sl; R.cpre[k]=run;
  }
  R.run = run;
}

// cs[idx], cs[idx+1] reconstructed from scan registers (uniform idx).
__device__ __forceinline__ void cs_pair_from_regs(int idx, float ex, const SegOut& R,
                                                  float& c0, float& c1){
  int o = idx >> 2, r = idx & 3;
  float a0 = (r==0)?0.f : (r==1)?R.cpre[0] : (r==2)?R.cpre[1] : R.cpre[2];
  float a1 = (r==0)?R.cpre[0] : (r==1)?R.cpre[1] : (r==2)?R.cpre[2] : R.run;
  c0 = rlane_f(ex + a0, idx >> 2);
  c1 = rlane_f(ex + a1, o);
}

// Unified fwd/rev timestep interpolation (single strict count).
__device__ __forceinline__ void interp_at(const float* __restrict__ pts,
                                          const float* __restrict__ cs,
                                          const float* co, float Tot, int nv, int jmaxv,
                                          int dir, float ts,
                                          float& prx, float& pry, float& prz){
  float vq = dir ? (Tot - ts) : bump(ts);
  int cnt = count256s(cs, co, vq);
  int j = dir ? (nv-1-cnt) : (cnt-1);
  j = j<0?0:(j>jmaxv?jmaxv:j);
  int ia = dir ? (nv-1-j) : j;
  int ib = dir ? (nv-2-j) : (j+1);
  int lo = dir ? ib : ia;
  float c_lo = cs[lo], c_hi = cs[lo+1];
  float base = dir ? (Tot - c_hi) : c_lo;
  float tl = (ts - base) * frcp(fmaxf(c_hi - c_lo, EPS_LEN));
  tl = fminf(fmaxf(tl,0.f),1.f);
  float3 PA = *(const float3*)(pts + ia*3);
  float3 PB = *(const float3*)(pts + ib*3);
  prx = PA.x + tl*(PB.x-PA.x);
  pry = PA.y + tl*(PB.y-PA.y);
  prz = PA.z + tl*(PB.z-PA.z);
}

// In-wave trajectory cum-arc-length -> s_tc[0..79] (this wave's LDS region).
// Also returns pos[lane] (ptl) and pos[64+lane] for lane<16 (pB) for reuse.
__device__ __forceinline__ void traj_tcs_wave(const float* __restrict__ pos, int lane,
                                              float* __restrict__ s_tc,
                                              float3& ptl, float3& pB){
  ptl.x = pos[lane*3+0]; ptl.y = pos[lane*3+1]; ptl.z = pos[lane*3+2];
  pB = make_float3(0.f,0.f,0.f);
  if (lane < 16){
    int t = 64+lane;
    pB.x = pos[t*3+0]; pB.y = pos[t*3+1]; pB.z = pos[t*3+2];
  }
  // chunk A: seg[l] = |pos[l+1]-pos[l]|, l = 0..63
  float nx = __shfl_down(ptl.x,1,64), ny = __shfl_down(ptl.y,1,64), nz = __shfl_down(ptl.z,1,64);
  float bx0 = rlane_f(pB.x,0), by0 = rlane_f(pB.y,0), bz0 = rlane_f(pB.z,0);
  if (lane==63){ nx=bx0; ny=by0; nz=bz0; }
  float dx=nx-ptl.x, dy=ny-ptl.y, dz=nz-ptl.z;
  float segA = fsq(dx*dx+dy*dy+dz*dz);
  // chunk B: seg[64+l], l = 0..14
  float mx = __shfl_down(pB.x,1,64), my = __shfl_down(pB.y,1,64), mz = __shfl_down(pB.z,1,64);
  float ex=mx-pB.x, ey=my-pB.y, ez=mz-pB.z;
  float segB = (lane<15) ? fsq(ex*ex+ey*ey+ez*ez) : 0.f;
  float incA = wave_incl_scan(segA);
  float totA = rlane_f(incA, 63);
  float incB = wave_incl_scan(segB);
  s_tc[lane+1] = incA;                       // tcs[1..64]
  if (lane<15) s_tc[65+lane] = totA + incB;  // tcs[65..79]
  if (lane==0) s_tc[0] = 0.f;
}

// K2: one wave per (n,b) -> both-direction costs + entry points. No K1.
__global__ __launch_bounds__(256, 8)
void cost_kernel(const float* __restrict__ traj, const float* __restrict__ rp,
                 const void* __restrict__ mask,
                 float* __restrict__ cost, float2* __restrict__ ent) {
  __shared__ float s_pts[4][NP*3], s_cs[4][NP], s_tc[4][TT];
  const int wid = threadIdx.x>>6, lane = threadIdx.x&63;
  const int nb = blockIdx.x*4 + wid;
  const int n = nb >> 4;                    // NBB == 16
  const float* pos = traj + (size_t)n*TT*3;

  // ---- issue all independent global loads first (rp NOT mask-predicated) ----
  const float4* p4 = (const float4*)(rp + (size_t)nb*NP*3);
  float4 A = p4[lane*3+0], B = p4[lane*3+1], C = p4[lane*3+2];
  int nvr = wave_nv(mask, (size_t)nb*NP, lane);
  float3 ptl, pB;
  traj_tcs_wave(pos, lane, s_tc[wid], ptl, pB);

  if (nvr < 2){
    if (lane==0){ cost[nb*2+0]=INFINITY; cost[nb*2+1]=INFINITY; }
    return;
  }
  const int nv = nvr;
  float p0x = rlane_f(ptl.x,0), p0y = rlane_f(ptl.y,0), p0z = rlane_f(ptl.z,0);

  SegOut R;
  seg_pass<true>(A,B,C, lane, nv, p0x,p0y,p0z, s_pts[wid], R);

  float inc = wave_incl_scan(R.run);
  float ex = inc - R.run;
  ((float4*)s_cs[wid])[lane] = make_float4(ex, ex+R.cpre[0], ex+R.cpre[1], ex+R.cpre[2]);
  const float Tot = rlane_f(inc, 63);

  float cval = ex + R.cpre[2];
  float co[16];
  #pragma unroll
  for (int k=0;k<16;k++) co[k] = rlane_f(cval, 4*k+3);

  float minv = wave_min_all(R.bdf);
  unsigned long long mf = __ballot(R.bdf == minv);
  unsigned long long ml = __ballot(R.bdl == minv);
  int lf = __builtin_ctzll(mf);
  int ll = 63 - __builtin_clzll(ml);
  int   jf = __builtin_amdgcn_readlane(R.bjf, lf);
  float tf = rlane_f(R.btf, lf);
  int   jl = __builtin_amdgcn_readlane(R.bjl, ll);
  float tl0 = rlane_f(R.btl, ll);
  float cjf, cjf1, cjl, cjl1;
  cs_pair_from_regs(jf, ex, R, cjf, cjf1);
  cs_pair_from_regs(jl, ex, R, cjl, cjl1);
  float e0 = cjf + tf*(cjf1-cjf);
  float e1 = (Tot - cjl1) + (1.f-tl0)*(cjl1-cjl);

  lds_fence();  // pts/cs/tc writes -> visible to cross-lane reads below

  const float* cs = s_cs[wid];
  const float* pts = s_pts[wid];
  const float* tcw = s_tc[wid];
  const int jmaxv = nv-2;
  float accf=0.f, accr=0.f;
  #pragma unroll
  for (int p=0;p<3;p++){
    int task = p*64 + lane;
    bool act = task < 2*TT;
    int dir = task>=TT ? 1 : 0;
    int t = dir ? task-TT : task;
    int tr = t < TT ? t : TT-1;
    float ts = (dir ? e1 : e0) + tcw[tr];
    ts = fminf(fmaxf(ts,0.f),Tot);
    float prx,pry,prz;
    interp_at(pts, cs, co, Tot, nv, jmaxv, dir, ts, prx,pry,prz);
    if (p==0){
      float dx=ptl.x-prx, dy=ptl.y-pry, dz=ptl.z-prz;   // t==lane
      accf += fsq(dx*dx+dy*dy+dz*dz);
    } else if (act){
      float px_, py_, pz_;
      if (p==1 && !dir){ px_=pB.x; py_=pB.y; pz_=pB.z; } // t==64+lane
      else { px_=pos[t*3+0]; py_=pos[t*3+1]; pz_=pos[t*3+2]; }
      float dx=px_-prx, dy=py_-pry, dz=pz_-prz;
      float dd=fsq(dx*dx+dy*dy+dz*dz);
      if (dir) accr+=dd; else accf+=dd;
    }
  }
  float cf = wave_sum(accf), cr = wave_sum(accr);
  if (lane==0){
    cost[nb*2+0]=cf; cost[nb*2+1]=cr;
    ent[nb] = make_float2(e0, e1);
  }
}

// K3: one wave per n -> argmin over 32 candidates, recompute winner, write out.
__global__ __launch_bounds__(256)
void winner_kernel(const float* __restrict__ traj, const float* __restrict__ rp,
                   const void* __restrict__ mask,
                   const float* __restrict__ cost, const float2* __restrict__ ent,
                   float* __restrict__ out) {
  __shared__ float s_pts[4][NP*3], s_cs[4][NP], s_tc[4][TT];
  const int wid = threadIdx.x>>6, lane = threadIdx.x&63;
  const int n = blockIdx.x*4 + wid;
  const float* c = cost + (size_t)n*NBB*2;
  float bc = (lane<NBB*2) ? c[lane] : INFINITY;
  int bi = (lane<NBB*2) ? lane : 64;
  #pragma unroll
  for (int d=1;d<64;d<<=1){
    float oc=__shfl_xor(bc,d,64); int oi=__shfl_xor(bi,d,64);
    if (oc<bc || (oc==bc && oi<bi)){bc=oc;bi=oi;}
  }
  const float* pos = traj + (size_t)n*TT*3;
  float* o = out + (size_t)n*TT*3;
  if (bc == INFINITY){  // no valid candidate: passthrough
    if (lane < 60) ((float4*)o)[lane] = ((const float4*)pos)[lane];
    return;
  }
  int b = bi>>1, dir = bi&1;
  const size_t nbi = (size_t)n*NBB + b;
  const float4* p4 = (const float4*)(rp + nbi*NP*3);
  float4 A = p4[lane*3+0], B = p4[lane*3+1], C = p4[lane*3+2];
  float2 eW = ent[nbi];
  float entry = dir ? eW.y : eW.x;
  int nv = wave_nv(mask, nbi*NP, lane);
  nv = max(nv, 2);
  float3 ptl, pB;
  traj_tcs_wave(pos, lane, s_tc[wid], ptl, pB);

  SegOut R;
  seg_pass<false>(A,B,C, lane, nv, 0.f,0.f,0.f, s_pts[wid], R);
  float inc = wave_incl_scan(R.run);
  float ex = inc - R.run;
  ((float4*)s_cs[wid])[lane] = make_float4(ex, ex+R.cpre[0], ex+R.cpre[1], ex+R.cpre[2]);
  const float Tot = rlane_f(inc, 63);
  float cval = ex + R.cpre[2];
  float co[16];
  #pragma unroll
  for (int k=0;k<16;k++) co[k] = rlane_f(cval, 4*k+3);

  lds_fence();

  const float* cs = s_cs[wid];
  const float* pts = s_pts[wid];
  const float* tcw = s_tc[wid];
  const int jmaxv = nv-2;
  #pragma unroll
  for (int p=0;p<2;p++){
    int t = p*64 + lane;
    int tr = t < TT ? t : TT-1;
    float ts = entry + tcw[tr];
    ts = fminf(fmaxf(ts,0.f),Tot);
    float prx,pry,prz;
    interp_at(pts, cs, co, Tot, nv, jmaxv, dir, ts, prx,pry,prz);
    if (t < TT){ o[t*3+0]=prx; o[t*3+1]=pry; o[t*3+2]=prz; }
  }
}

extern "C" void kernel_launch(void* const* d_in, const int* in_sizes, int n_in,
                              void* d_out, int out_size, void* d_ws, size_t ws_size,
                              hipStream_t stream) {
  const float* traj = (const float*)d_in[0];
  const float* rp   = (const float*)d_in[1];
  const void*  mask = d_in[2];
  float* cost = (float*)d_ws;                        // NN*NBB*2 floats
  float2* ent = (float2*)(cost + (size_t)NN*NBB*2);  // NN*NBB float2
  float* out  = (float*)d_out;

  hipLaunchKernelGGL(cost_kernel, dim3(NN*NBB/4), dim3(256), 0, stream,
                     traj, rp, mask, cost, ent);
  hipLaunchKernelGGL(winner_kernel, dim3(NN/4), dim3(256), 0, stream,
                     traj, rp, mask, cost, ent, out);
}

// Round 11
// 30.918 us; speedup vs baseline: 7.9158x; 1.0330x over previous
//
#include <hip/hip_runtime.h>
#include <math.h>

#define NN 1024
#define NBB 16
#define NP 256
#define TT 80
#define EPS_LEN 1e-9f
#define EPS_DD 1e-12f

__device__ __forceinline__ float frcp(float x){ return __builtin_amdgcn_rcpf(x); }
__device__ __forceinline__ float fsq(float x){ return __builtin_amdgcn_sqrtf(x); }
__device__ __forceinline__ float rlane_f(float x, int l){
  return __builtin_bit_cast(float, __builtin_amdgcn_readlane(__builtin_bit_cast(int, x), l));
}
// count(c <= v) == count(c < bump(v)) exactly for nonneg floats
__device__ __forceinline__ float bump(float v){
  return __builtin_bit_cast(float, __builtin_bit_cast(int, v) + 1);
}

// ---- DPP wave64 primitives (canonical gfx9 sequence; validated R6-R9) ----
template<int CTRL,int RM>
__device__ __forceinline__ float dpp_add(float v){
  int t = __builtin_amdgcn_update_dpp(0, __builtin_bit_cast(int, v), CTRL, RM, 0xf, true);
  return v + __builtin_bit_cast(float, t);
}
__device__ __forceinline__ float wave_incl_scan(float v){
  v = dpp_add<0x111,0xf>(v);   // row_shr:1
  v = dpp_add<0x112,0xf>(v);   // row_shr:2
  v = dpp_add<0x114,0xf>(v);   // row_shr:4
  v = dpp_add<0x118,0xf>(v);   // row_shr:8
  v = dpp_add<0x142,0xa>(v);   // row_bcast:15 -> rows 1,3
  v = dpp_add<0x143,0xc>(v);   // row_bcast:31 -> rows 2,3
  return v;
}
__device__ __forceinline__ float wave_sum(float v){ return rlane_f(wave_incl_scan(v), 63); }
template<int CTRL,int RM>
__device__ __forceinline__ float dpp_min(float v){
  int t = __builtin_amdgcn_update_dpp(0x7f800000, __builtin_bit_cast(int,v), CTRL, RM, 0xf, false);
  return fminf(v, __builtin_bit_cast(float,t));
}
__device__ __forceinline__ float wave_min_all(float v){
  v=dpp_min<0x111,0xf>(v); v=dpp_min<0x112,0xf>(v);
  v=dpp_min<0x114,0xf>(v); v=dpp_min<0x118,0xf>(v);
  v=dpp_min<0x142,0xa>(v); v=dpp_min<0x143,0xc>(v);
  return rlane_f(v, 63);
}

// Wave-synchronous LDS fence (per-wave LDS regions; no __syncthreads needed).
__device__ __forceinline__ void lds_fence() {
  __builtin_amdgcn_wave_barrier();
  asm volatile("s_waitcnt lgkmcnt(0)" ::: "memory");
  __builtin_amdgcn_wave_barrier();
}

// n_valid, wave-wide. Mask layout auto-detect: byte[1] of buffer != 0 -> bool
// bytes (mask[0][0][1] true since lengths>=2); int32 layout -> that byte is 0.
__device__ __forceinline__ int wave_nv(const void* mask, size_t base, int lane) {
  bool as_byte = ((const unsigned char*)mask)[1] != 0;
  int nv = 0;
  if (as_byte) {
    uchar4 v = ((const uchar4*)((const unsigned char*)mask + base))[lane];
    nv += __popcll(__ballot(v.x != 0));
    nv += __popcll(__ballot(v.y != 0));
    nv += __popcll(__ballot(v.z != 0));
    nv += __popcll(__ballot(v.w != 0));
  } else {
    int4 v = ((const int4*)((const int*)mask + base))[lane];
    nv += __popcll(__ballot(v.x != 0));
    nv += __popcll(__ballot(v.y != 0));
    nv += __popcll(__ballot(v.z != 0));
    nv += __popcll(__ballot(v.w != 0));
  }
  return nv;
}

// Count of entries in cs[0..255] strictly < v. co[16] wave-uniform,
// co[k] = cs[16k+15]. Non-strict counts use bump(v).
__device__ __forceinline__ int count256s(const float* __restrict__ cs,
                                         const float* co, float v){
  int K = 0;
  #pragma unroll
  for (int k=0;k<16;k++) K += (co[k] < v);
  int base = (K < 16 ? K : 15) * 16;
  const float4* f4 = (const float4*)(cs + base);
  float4 c0=f4[0], c1=f4[1], c2=f4[2], c3=f4[3];
  int r = (c0.x<v)+(c0.y<v)+(c0.z<v)+(c0.w<v)+(c1.x<v)+(c1.y<v)+(c1.z<v)+(c1.w<v)
        + (c2.x<v)+(c2.y<v)+(c2.z<v)+(c2.w<v)+(c3.x<v)+(c3.y<v)+(c3.z<v)+(c3.w<v);
  return (K >= 16) ? 256 : (base + r);
}

struct SegOut {
  float cpre[4];
  float run;
  float bdf, btf; int bjf;   // per-lane first-min (fwd)
  float bdl, btl; int bjl;   // per-lane last-min  (rev)
};

// Segment pass on preloaded point regs; stages packed [256][3] pts to LDS.
template<bool NEEDMIN>
__device__ __forceinline__ void seg_pass(float4 A, float4 B, float4 C,
                                         int lane, int nv,
                                         float p0x, float p0y, float p0z,
                                         float* __restrict__ pts, SegOut& R) {
  const int j0 = lane * 4;
  float x[5], y[5], z[5];
  x[0]=A.x; y[0]=A.y; z[0]=A.z;
  x[1]=A.w; y[1]=B.x; z[1]=B.y;
  x[2]=B.z; y[2]=B.w; z[2]=C.x;
  x[3]=C.y; y[3]=C.z; z[3]=C.w;
  x[4]=__shfl_down(x[0],1,64); y[4]=__shfl_down(y[0],1,64); z[4]=__shfl_down(z[0],1,64);
  ((float4*)pts)[lane*3+0] = make_float4(x[0],y[0],z[0],x[1]);
  ((float4*)pts)[lane*3+1] = make_float4(y[1],z[1],x[2],y[2]);
  ((float4*)pts)[lane*3+2] = make_float4(z[2],x[3],y[3],z[3]);
  float run = 0.f;
  R.bdf=INFINITY; R.btf=0.f; R.bjf=j0;
  R.bdl=INFINITY; R.btl=0.f; R.bjl=j0;
  #pragma unroll
  for (int k=0;k<4;k++){
    bool valid = (j0+k) < nv-1;
    float vx=x[k+1]-x[k], vy=y[k+1]-y[k], vz=z[k+1]-z[k];
    float n2 = vx*vx+vy*vy+vz*vz;
    float sl = valid ? fmaxf(fsq(n2), EPS_LEN) : 0.f;
    if (NEEDMIN){
      float t = ((p0x-x[k])*vx+(p0y-y[k])*vy+(p0z-z[k])*vz) * frcp(fmaxf(n2,EPS_DD));
      t = fminf(fmaxf(t,0.f),1.f);
      float qx=x[k]+t*vx, qy=y[k]+t*vy, qz=z[k]+t*vz;
      float dx=p0x-qx, dy=p0y-qy, dz=p0z-qz;
      float d2 = valid ? (dx*dx+dy*dy+dz*dz) : INFINITY;
      if (d2 <  R.bdf){R.bdf=d2; R.bjf=j0+k; R.btf=t;}
      if (d2 <= R.bdl){R.bdl=d2; R.bjl=j0+k; R.btl=t;}
    }
    run += sl; R.cpre[k]=run;
  }
  R.run = run;
}

// cs[idx], cs[idx+1] reconstructed from scan registers (uniform idx).
__device__ __forceinline__ void cs_pair_from_regs(int idx, float ex, const SegOut& R,
                                                  float& c0, float& c1){
  int o = idx >> 2, r = idx & 3;
  float a0 = (r==0)?0.f : (r==1)?R.cpre[0] : (r==2)?R.cpre[1] : R.cpre[2];
  float a1 = (r==0)?R.cpre[0] : (r==1)?R.cpre[1] : (r==2)?R.cpre[2] : R.run;
  c0 = rlane_f(ex + a0, o);
  c1 = rlane_f(ex + a1, o);
}

// Unified fwd/rev timestep interpolation (single strict count).
__device__ __forceinline__ void interp_at(const float* __restrict__ pts,
                                          const float* __restrict__ cs,
                                          const float* co, float Tot, int nv, int jmaxv,
                                          int dir, float ts,
                                          float& prx, float& pry, float& prz){
  float vq = dir ? (Tot - ts) : bump(ts);
  int cnt = count256s(cs, co, vq);
  int j = dir ? (nv-1-cnt) : (cnt-1);
  j = j<0?0:(j>jmaxv?jmaxv:j);
  int ia = dir ? (nv-1-j) : j;
  int ib = dir ? (nv-2-j) : (j+1);
  int lo = dir ? ib : ia;
  float c_lo = cs[lo], c_hi = cs[lo+1];
  float base = dir ? (Tot - c_hi) : c_lo;
  float tl = (ts - base) * frcp(fmaxf(c_hi - c_lo, EPS_LEN));
  tl = fminf(fmaxf(tl,0.f),1.f);
  float3 PA = *(const float3*)(pts + ia*3);
  float3 PB = *(const float3*)(pts + ib*3);
  prx = PA.x + tl*(PB.x-PA.x);
  pry = PA.y + tl*(PB.y-PA.y);
  prz = PA.z + tl*(PB.z-PA.z);
}

// In-wave trajectory cum-arc-length -> s_tc[0..79] (this wave's LDS region).
// Also returns pos[lane] (ptl) and pos[64+lane] for lane<16 (pB).
__device__ __forceinline__ void traj_tcs_wave(const float* __restrict__ pos, int lane,
                                              float* __restrict__ s_tc,
                                              float3& ptl, float3& pB){
  ptl.x = pos[lane*3+0]; ptl.y = pos[lane*3+1]; ptl.z = pos[lane*3+2];
  pB = make_float3(0.f,0.f,0.f);
  if (lane < 16){
    int t = 64+lane;
    pB.x = pos[t*3+0]; pB.y = pos[t*3+1]; pB.z = pos[t*3+2];
  }
  float nx = __shfl_down(ptl.x,1,64), ny = __shfl_down(ptl.y,1,64), nz = __shfl_down(ptl.z,1,64);
  float bx0 = rlane_f(pB.x,0), by0 = rlane_f(pB.y,0), bz0 = rlane_f(pB.z,0);
  if (lane==63){ nx=bx0; ny=by0; nz=bz0; }
  float dx=nx-ptl.x, dy=ny-ptl.y, dz=nz-ptl.z;
  float segA = fsq(dx*dx+dy*dy+dz*dz);
  float mx = __shfl_down(pB.x,1,64), my = __shfl_down(pB.y,1,64), mz = __shfl_down(pB.z,1,64);
  float ex=mx-pB.x, ey=my-pB.y, ez=mz-pB.z;
  float segB = (lane<15) ? fsq(ex*ex+ey*ey+ez*ez) : 0.f;
  float incA = wave_incl_scan(segA);
  float totA = rlane_f(incA, 63);
  float incB = wave_incl_scan(segB);
  s_tc[lane+1] = incA;
  if (lane<15) s_tc[65+lane] = totA + incB;
  if (lane==0) s_tc[0] = 0.f;
}

// Single fused kernel: block = one n, 8 waves x 2 candidates each, then
// intra-block argmin + winner recompute by waves 0/1. No cross-block comm.
__global__ __launch_bounds__(512, 8)
void fused_all(const float* __restrict__ traj, const float* __restrict__ rp,
               const void* __restrict__ mask, float* __restrict__ out) {
  __shared__ float s_pts[8][NP*3];
  __shared__ float s_cs[8][NP];
  __shared__ float s_tc[8][TT];
  __shared__ float s_cost[NBB*2];
  __shared__ float2 s_ent[NBB];

  const int wid = threadIdx.x>>6, lane = threadIdx.x&63;
  const int n = blockIdx.x;
  const float* pos = traj + (size_t)n*TT*3;

  float3 ptl, pB;
  traj_tcs_wave(pos, lane, s_tc[wid], ptl, pB);
  const float p0x = rlane_f(ptl.x,0), p0y = rlane_f(ptl.y,0), p0z = rlane_f(ptl.z,0);

  float* pts = s_pts[wid];
  float* csb = s_cs[wid];
  const float* tcw = s_tc[wid];

  #pragma unroll 1
  for (int c=0; c<2; ++c){
    const int b = wid*2 + c;
    const size_t nb = (size_t)n*NBB + b;
    const float4* p4 = (const float4*)(rp + nb*NP*3);
    float4 A = p4[lane*3+0], B = p4[lane*3+1], C = p4[lane*3+2];
    int nv = wave_nv(mask, nb*NP, lane);
    float cf = INFINITY, cr = INFINITY, e0 = 0.f, e1 = 0.f;
    if (nv >= 2){
      SegOut R;
      seg_pass<true>(A,B,C, lane, nv, p0x,p0y,p0z, pts, R);
      float inc = wave_incl_scan(R.run);
      float ex = inc - R.run;
      ((float4*)csb)[lane] = make_float4(ex, ex+R.cpre[0], ex+R.cpre[1], ex+R.cpre[2]);
      const float Tot = rlane_f(inc, 63);
      float cval = ex + R.cpre[2];
      float co[16];
      #pragma unroll
      for (int k=0;k<16;k++) co[k] = rlane_f(cval, 4*k+3);
      float minv = wave_min_all(R.bdf);
      unsigned long long mf = __ballot(R.bdf == minv);
      unsigned long long ml = __ballot(R.bdl == minv);
      int lf = __builtin_ctzll(mf);
      int ll = 63 - __builtin_clzll(ml);
      int   jf = __builtin_amdgcn_readlane(R.bjf, lf);
      float tf = rlane_f(R.btf, lf);
      int   jl = __builtin_amdgcn_readlane(R.bjl, ll);
      float tl0 = rlane_f(R.btl, ll);
      float cjf, cjf1, cjl, cjl1;
      cs_pair_from_regs(jf, ex, R, cjf, cjf1);
      cs_pair_from_regs(jl, ex, R, cjl, cjl1);
      e0 = cjf + tf*(cjf1-cjf);
      e1 = (Tot - cjl1) + (1.f-tl0)*(cjl1-cjl);

      lds_fence();

      const int jmaxv = nv-2;
      float accf=0.f, accr=0.f;
      #pragma unroll
      for (int p=0;p<3;p++){
        int task = p*64 + lane;
        bool act = task < 2*TT;
        int dir = task>=TT ? 1 : 0;
        int t = dir ? task-TT : task;
        int tr = t < TT ? t : TT-1;
        float ts = (dir ? e1 : e0) + tcw[tr];
        ts = fminf(fmaxf(ts,0.f),Tot);
        float prx,pry,prz;
        interp_at(pts, csb, co, Tot, nv, jmaxv, dir, ts, prx,pry,prz);
        if (p==0){
          float dx=ptl.x-prx, dy=ptl.y-pry, dz=ptl.z-prz;   // t==lane
          accf += fsq(dx*dx+dy*dy+dz*dz);
        } else if (act){
          float px_, py_, pz_;
          if (p==1 && !dir){ px_=pB.x; py_=pB.y; pz_=pB.z; } // t==64+lane
          else { px_=pos[t*3+0]; py_=pos[t*3+1]; pz_=pos[t*3+2]; }
          float dx=px_-prx, dy=py_-pry, dz=pz_-prz;
          float dd=fsq(dx*dx+dy*dy+dz*dz);
          if (dir) accr+=dd; else accf+=dd;
        }
      }
      cf = wave_sum(accf); cr = wave_sum(accr);
      lds_fence();   // csb/pts reads done before candidate c=1 overwrites
    }
    if (lane==0){
      s_cost[b*2+0]=cf; s_cost[b*2+1]=cr;
      s_ent[b] = make_float2(e0, e1);
    }
  }

  __syncthreads();   // all 32 costs + entries visible block-wide
  if (wid >= 2) return;

  // ---- winner phase: waves 0 and 1 ----
  float bc = (lane<NBB*2) ? s_cost[lane] : INFINITY;
  int bi = (lane<NBB*2) ? lane : 64;
  #pragma unroll
  for (int d=1;d<64;d<<=1){
    float oc=__shfl_xor(bc,d,64); int oi=__shfl_xor(bi,d,64);
    if (oc<bc || (oc==bc && oi<bi)){bc=oc;bi=oi;}
  }
  float* o = out + (size_t)n*TT*3;
  if (bc == INFINITY){   // no valid candidate: passthrough
    if (wid==0 && lane < 60) ((float4*)o)[lane] = ((const float4*)pos)[lane];
    return;
  }
  int b = bi>>1, dir = bi&1;
  const size_t nbi = (size_t)n*NBB + b;
  const float4* p4 = (const float4*)(rp + nbi*NP*3);
  float4 A = p4[lane*3+0], B = p4[lane*3+1], C = p4[lane*3+2];
  float2 eW = s_ent[b];
  float entry = dir ? eW.y : eW.x;
  int nv = wave_nv(mask, nbi*NP, lane);
  nv = max(nv, 2);

  SegOut R;
  seg_pass<false>(A,B,C, lane, nv, 0.f,0.f,0.f, pts, R);
  float inc = wave_incl_scan(R.run);
  float ex = inc - R.run;
  ((float4*)csb)[lane] = make_float4(ex, ex+R.cpre[0], ex+R.cpre[1], ex+R.cpre[2]);
  const float Tot = rlane_f(inc, 63);
  float cval = ex + R.cpre[2];
  float co[16];
  #pragma unroll
  for (int k=0;k<16;k++) co[k] = rlane_f(cval, 4*k+3);

  lds_fence();

  const int jmaxv = nv-2;
  int t = wid*40 + lane;          // wave0: 0..39, wave1: 40..79
  if (lane < 40){
    float ts = entry + tcw[t];
    ts = fminf(fmaxf(ts,0.f),Tot);
    float prx,pry,prz;
    interp_at(pts, csb, co, Tot, nv, jmaxv, dir, ts, prx,pry,prz);
    o[t*3+0]=prx; o[t*3+1]=pry; o[t*3+2]=prz;
  }
}

extern "C" void kernel_launch(void* const* d_in, const int* in_sizes, int n_in,
                              void* d_out, int out_size, void* d_ws, size_t ws_size,
                              hipStream_t stream) {
  const float* traj = (const float*)d_in[0];
  const float* rp   = (const float*)d_in[1];
  const void*  mask = d_in[2];
  float* out  = (float*)d_out;
  hipLaunchKernelGGL(fused_all, dim3(NN), dim3(512), 0, stream,
                     traj, rp, mask, out);
}

// Round 12
// 30.361 us; speedup vs baseline: 8.0611x; 1.0184x over previous
//
#include <hip/hip_runtime.h>
#include <math.h>

#define NN 1024
#define NBB 16
#define NP 256
#define TT 80
#define EPS_LEN 1e-9f
#define EPS_DD 1e-12f

__device__ __forceinline__ float frcp(float x){ return __builtin_amdgcn_rcpf(x); }
__device__ __forceinline__ float fsq(float x){ return __builtin_amdgcn_sqrtf(x); }
__device__ __forceinline__ float rlane_f(float x, int l){
  return __builtin_bit_cast(float, __builtin_amdgcn_readlane(__builtin_bit_cast(int, x), l));
}
// count(c <= v) == count(c < bump(v)) exactly for nonneg floats
__device__ __forceinline__ float bump(float v){
  return __builtin_bit_cast(float, __builtin_bit_cast(int, v) + 1);
}

// ---- DPP wave64 primitives (validated R6-R10) ----
template<int CTRL,int RM>
__device__ __forceinline__ float dpp_add(float v){
  int t = __builtin_amdgcn_update_dpp(0, __builtin_bit_cast(int, v), CTRL, RM, 0xf, true);
  return v + __builtin_bit_cast(float, t);
}
__device__ __forceinline__ float wave_incl_scan(float v){
  v = dpp_add<0x111,0xf>(v);
  v = dpp_add<0x112,0xf>(v);
  v = dpp_add<0x114,0xf>(v);
  v = dpp_add<0x118,0xf>(v);
  v = dpp_add<0x142,0xa>(v);
  v = dpp_add<0x143,0xc>(v);
  return v;
}
__device__ __forceinline__ float wave_sum(float v){ return rlane_f(wave_incl_scan(v), 63); }
template<int CTRL,int RM>
__device__ __forceinline__ float dpp_min(float v){
  int t = __builtin_amdgcn_update_dpp(0x7f800000, __builtin_bit_cast(int,v), CTRL, RM, 0xf, false);
  return fminf(v, __builtin_bit_cast(float,t));
}
__device__ __forceinline__ float wave_min_all(float v){
  v=dpp_min<0x111,0xf>(v); v=dpp_min<0x112,0xf>(v);
  v=dpp_min<0x114,0xf>(v); v=dpp_min<0x118,0xf>(v);
  v=dpp_min<0x142,0xa>(v); v=dpp_min<0x143,0xc>(v);
  return rlane_f(v, 63);
}

// Wave-synchronous LDS fence (own-region write->read ordering).
__device__ __forceinline__ void lds_fence() {
  __builtin_amdgcn_wave_barrier();
  asm volatile("s_waitcnt lgkmcnt(0)" ::: "memory");
  __builtin_amdgcn_wave_barrier();
}

// n_valid, wave-wide. Mask layout auto-detect: byte[1] != 0 -> bool bytes.
__device__ __forceinline__ int wave_nv(const void* mask, size_t base, int lane) {
  bool as_byte = ((const unsigned char*)mask)[1] != 0;
  int nv = 0;
  if (as_byte) {
    uchar4 v = ((const uchar4*)((const unsigned char*)mask + base))[lane];
    nv += __popcll(__ballot(v.x != 0));
    nv += __popcll(__ballot(v.y != 0));
    nv += __popcll(__ballot(v.z != 0));
    nv += __popcll(__ballot(v.w != 0));
  } else {
    int4 v = ((const int4*)((const int*)mask + base))[lane];
    nv += __popcll(__ballot(v.x != 0));
    nv += __popcll(__ballot(v.y != 0));
    nv += __popcll(__ballot(v.z != 0));
    nv += __popcll(__ballot(v.w != 0));
  }
  return nv;
}

// Count entries in cs[0..255] strictly < v; co[16] wave-uniform coarse table.
__device__ __forceinline__ int count256s(const float* __restrict__ cs,
                                         const float* co, float v){
  int K = 0;
  #pragma unroll
  for (int k=0;k<16;k++) K += (co[k] < v);
  int base = (K < 16 ? K : 15) * 16;
  const float4* f4 = (const float4*)(cs + base);
  float4 c0=f4[0], c1=f4[1], c2=f4[2], c3=f4[3];
  int r = (c0.x<v)+(c0.y<v)+(c0.z<v)+(c0.w<v)+(c1.x<v)+(c1.y<v)+(c1.z<v)+(c1.w<v)
        + (c2.x<v)+(c2.y<v)+(c2.z<v)+(c2.w<v)+(c3.x<v)+(c3.y<v)+(c3.z<v)+(c3.w<v);
  return (K >= 16) ? 256 : (base + r);
}

struct SegOut {
  float cpre[4];
  float run;
  float bdf, btf; int bjf;
  float bdl, btl; int bjl;
};

template<bool NEEDMIN>
__device__ __forceinline__ void seg_pass(float4 A, float4 B, float4 C,
                                         int lane, int nv,
                                         float p0x, float p0y, float p0z,
                                         float* __restrict__ pts, SegOut& R) {
  const int j0 = lane * 4;
  float x[5], y[5], z[5];
  x[0]=A.x; y[0]=A.y; z[0]=A.z;
  x[1]=A.w; y[1]=B.x; z[1]=B.y;
  x[2]=B.z; y[2]=B.w; z[2]=C.x;
  x[3]=C.y; y[3]=C.z; z[3]=C.w;
  x[4]=__shfl_down(x[0],1,64); y[4]=__shfl_down(y[0],1,64); z[4]=__shfl_down(z[0],1,64);
  ((float4*)pts)[lane*3+0] = make_float4(x[0],y[0],z[0],x[1]);
  ((float4*)pts)[lane*3+1] = make_float4(y[1],z[1],x[2],y[2]);
  ((float4*)pts)[lane*3+2] = make_float4(z[2],x[3],y[3],z[3]);
  float run = 0.f;
  R.bdf=INFINITY; R.btf=0.f; R.bjf=j0;
  R.bdl=INFINITY; R.btl=0.f; R.bjl=j0;
  #pragma unroll
  for (int k=0;k<4;k++){
    bool valid = (j0+k) < nv-1;
    float vx=x[k+1]-x[k], vy=y[k+1]-y[k], vz=z[k+1]-z[k];
    float n2 = vx*vx+vy*vy+vz*vz;
    float sl = valid ? fmaxf(fsq(n2), EPS_LEN) : 0.f;
    if (NEEDMIN){
      float t = ((p0x-x[k])*vx+(p0y-y[k])*vy+(p0z-z[k])*vz) * frcp(fmaxf(n2,EPS_DD));
      t = fminf(fmaxf(t,0.f),1.f);
      float qx=x[k]+t*vx, qy=y[k]+t*vy, qz=z[k]+t*vz;
      float dx=p0x-qx, dy=p0y-qy, dz=p0z-qz;
      float d2 = valid ? (dx*dx+dy*dy+dz*dz) : INFINITY;
      if (d2 <  R.bdf){R.bdf=d2; R.bjf=j0+k; R.btf=t;}
      if (d2 <= R.bdl){R.bdl=d2; R.bjl=j0+k; R.btl=t;}
    }
    run += sl; R.cpre[k]=run;
  }
  R.run = run;
}

__device__ __forceinline__ void cs_pair_from_regs(int idx, float ex, const SegOut& R,
                                                  float& c0, float& c1){
  int o = idx >> 2, r = idx & 3;
  float a0 = (r==0)?0.f : (r==1)?R.cpre[0] : (r==2)?R.cpre[1] : R.cpre[2];
  float a1 = (r==0)?R.cpre[0] : (r==1)?R.cpre[1] : (r==2)?R.cpre[2] : R.run;
  c0 = rlane_f(ex + a0, o);
  c1 = rlane_f(ex + a1, o);
}

// Unified fwd/rev timestep interpolation (single strict count).
__device__ __forceinline__ void interp_at(const float* __restrict__ pts,
                                          const float* __restrict__ cs,
                                          const float* co, float Tot, int nv, int jmaxv,
                                          int dir, float ts,
                                          float& prx, float& pry, float& prz){
  float vq = dir ? (Tot - ts) : bump(ts);
  int cnt = count256s(cs, co, vq);
  int j = dir ? (nv-1-cnt) : (cnt-1);
  j = j<0?0:(j>jmaxv?jmaxv:j);
  int ia = dir ? (nv-1-j) : j;
  int ib = dir ? (nv-2-j) : (j+1);
  int lo = dir ? ib : ia;
  float c_lo = cs[lo], c_hi = cs[lo+1];
  float base = dir ? (Tot - c_hi) : c_lo;
  float tl = (ts - base) * frcp(fmaxf(c_hi - c_lo, EPS_LEN));
  tl = fminf(fmaxf(tl,0.f),1.f);
  float3 PA = *(const float3*)(pts + ia*3);
  float3 PB = *(const float3*)(pts + ib*3);
  prx = PA.x + tl*(PB.x-PA.x);
  pry = PA.y + tl*(PB.y-PA.y);
  prz = PA.z + tl*(PB.z-PA.z);
}

// tcs[i] from this wave's trajectory scan registers (no LDS):
// i in [0,63]: exclusive A-scan at lane i; i==64: totA; i in [65,79]: tBv at lane i-65.
__device__ __forceinline__ float tc_of(int i, float exclA, float totA, float tBv){
  float vA = __shfl(exclA, i, 64);
  float vB = __shfl(tBv, i - 65, 64);
  return (i < 64) ? vA : ((i == 64) ? totA : vB);
}

// Single fused kernel. Block = one n, 16 waves x 1 candidate. Winner phase
// reads the winning candidate's resident LDS region -- no recompute.
__global__ __launch_bounds__(1024, 8)
void fused_all(const float* __restrict__ traj, const float* __restrict__ rp,
               const void* __restrict__ mask, float* __restrict__ ws,
               float* __restrict__ out) {
  __shared__ float s_pts[NBB][NP*3];   // 48 KB
  __shared__ float s_cs[NBB][NP];      // 16 KB  (total exactly 64 KB)

  const int wid = threadIdx.x>>6, lane = threadIdx.x&63;
  const int n = blockIdx.x;
  const float* pos = traj + (size_t)n*TT*3;
  float* wcost = ws + (size_t)n*96;    // 32 cost | 32 ent | 16 tot | 16 nv
  float* went  = wcost + 32;
  float* wtot  = wcost + 64;
  int*   wnv   = (int*)(wcost + 80);

  // ---- trajectory cum-arc-length in registers (identical across waves) ----
  float3 ptl, pB;
  ptl.x=pos[lane*3+0]; ptl.y=pos[lane*3+1]; ptl.z=pos[lane*3+2];
  pB = make_float3(0.f,0.f,0.f);
  if (lane < 16){
    int t = 64+lane;
    pB.x=pos[t*3+0]; pB.y=pos[t*3+1]; pB.z=pos[t*3+2];
  }
  float nx=__shfl_down(ptl.x,1,64), ny=__shfl_down(ptl.y,1,64), nz=__shfl_down(ptl.z,1,64);
  if (lane==63){ nx=rlane_f(pB.x,0); ny=rlane_f(pB.y,0); nz=rlane_f(pB.z,0); }
  float dxa=nx-ptl.x, dya=ny-ptl.y, dza=nz-ptl.z;
  float segA = fsq(dxa*dxa+dya*dya+dza*dza);
  float mx=__shfl_down(pB.x,1,64), my=__shfl_down(pB.y,1,64), mz=__shfl_down(pB.z,1,64);
  float exb=mx-pB.x, eyb=my-pB.y, ezb=mz-pB.z;
  float segB = (lane<15) ? fsq(exb*exb+eyb*eyb+ezb*ezb) : 0.f;
  float incA = wave_incl_scan(segA);
  float exclA = incA - segA;           // exclA[0] == 0 exactly
  float totA = rlane_f(incA, 63);
  float tBv = totA + wave_incl_scan(segB);
  const float p0x = rlane_f(ptl.x,0), p0y = rlane_f(ptl.y,0), p0z = rlane_f(ptl.z,0);

  // ---- candidate eval: wave wid owns boundary b = wid ----
  const int b = wid;
  const size_t nb = (size_t)n*NBB + b;
  const float4* p4 = (const float4*)(rp + nb*NP*3);
  float4 A = p4[lane*3+0], Bq = p4[lane*3+1], Cq = p4[lane*3+2];
  int nv = wave_nv(mask, nb*NP, lane);
  float* pts = s_pts[wid];
  float* csb = s_cs[wid];
  float cf=INFINITY, cr=INFINITY, e0=0.f, e1=0.f, Tot=0.f;

  if (nv >= 2){
    SegOut R;
    seg_pass<true>(A,Bq,Cq, lane, nv, p0x,p0y,p0z, pts, R);
    float inc = wave_incl_scan(R.run);
    float ex = inc - R.run;
    ((float4*)csb)[lane] = make_float4(ex, ex+R.cpre[0], ex+R.cpre[1], ex+R.cpre[2]);
    Tot = rlane_f(inc, 63);
    float cval = ex + R.cpre[2];
    float co[16];
    #pragma unroll
    for (int k=0;k<16;k++) co[k] = rlane_f(cval, 4*k+3);
    float minv = wave_min_all(R.bdf);
    unsigned long long mf = __ballot(R.bdf == minv);
    unsigned long long ml = __ballot(R.bdl == minv);
    int lf = __builtin_ctzll(mf);
    int ll = 63 - __builtin_clzll(ml);
    int   jf = __builtin_amdgcn_readlane(R.bjf, lf);
    float tf = rlane_f(R.btf, lf);
    int   jl = __builtin_amdgcn_readlane(R.bjl, ll);
    float tl0 = rlane_f(R.btl, ll);
    float cjf, cjf1, cjl, cjl1;
    cs_pair_from_regs(jf, ex, R, cjf, cjf1);
    cs_pair_from_regs(jl, ex, R, cjl, cjl1);
    e0 = cjf + tf*(cjf1-cjf);
    e1 = (Tot - cjl1) + (1.f-tl0)*(cjl1-cjl);

    lds_fence();   // own pts/cs writes -> cross-lane reads below

    const int jmaxv = nv-2;
    float accf=0.f, accr=0.f;
    #pragma unroll
    for (int p=0;p<3;p++){
      int task = p*64 + lane;
      bool act = task < 2*TT;
      int dir = task>=TT ? 1 : 0;
      int t = dir ? task-TT : task;
      int tr = t < TT ? t : TT-1;
      float ts = (dir ? e1 : e0) + tc_of(tr, exclA, totA, tBv);
      ts = fminf(fmaxf(ts,0.f),Tot);
      float prx,pry,prz;
      interp_at(pts, csb, co, Tot, nv, jmaxv, dir, ts, prx,pry,prz);
      if (p==0){
        float dx=ptl.x-prx, dy=ptl.y-pry, dz=ptl.z-prz;    // t==lane
        accf += fsq(dx*dx+dy*dy+dz*dz);
      } else if (act){
        float px_, py_, pz_;
        if (p==1 && !dir){ px_=pB.x; py_=pB.y; pz_=pB.z; }  // t==64+lane
        else { px_=pos[t*3+0]; py_=pos[t*3+1]; pz_=pos[t*3+2]; }
        float dx=px_-prx, dy=py_-pry, dz=pz_-prz;
        float dd=fsq(dx*dx+dy*dy+dz*dz);
        if (dir) accr+=dd; else accf+=dd;
      }
    }
    cf = wave_sum(accf); cr = wave_sum(accr);
  }
  if (lane==0){
    wcost[b*2+0]=cf; wcost[b*2+1]=cr;
    went [b*2+0]=e0; went [b*2+1]=e1;
    wtot[b]=Tot; wnv[b]=nv;
  }

  __syncthreads();   // drains global stores (vmcnt 0) + makes LDS block-visible
  if (wid != 0) return;

  // ---- winner phase: wave 0 only; zero recompute ----
  float bc = (lane < NBB*2)
    ? __hip_atomic_load(&wcost[lane], __ATOMIC_RELAXED, __HIP_MEMORY_SCOPE_AGENT)
    : INFINITY;
  int bi = (lane < NBB*2) ? lane : 64;
  #pragma unroll
  for (int d=1;d<64;d<<=1){
    float oc=__shfl_xor(bc,d,64); int oi=__shfl_xor(bi,d,64);
    if (oc<bc || (oc==bc && oi<bi)){bc=oc;bi=oi;}
  }
  float* o = out + (size_t)n*TT*3;
  if (bc == INFINITY){   // no valid candidate: passthrough
    if (lane < 60) ((float4*)o)[lane] = ((const float4*)pos)[lane];
    return;
  }
  int wb = bi>>1, dir = bi&1;
  float entry = __hip_atomic_load(&went[bi], __ATOMIC_RELAXED, __HIP_MEMORY_SCOPE_AGENT);
  float TotW  = __hip_atomic_load(&wtot[wb], __ATOMIC_RELAXED, __HIP_MEMORY_SCOPE_AGENT);
  int   nvW   = __hip_atomic_load(&wnv[wb],  __ATOMIC_RELAXED, __HIP_MEMORY_SCOPE_AGENT);
  const float* ptsW = s_pts[wb];
  const float* csW  = s_cs[wb];
  float cobk = (lane<16) ? csW[lane*16+15] : 0.f;
  float coW[16];
  #pragma unroll
  for (int k=0;k<16;k++) coW[k] = rlane_f(cobk, k);
  const int jmaxv = nvW-2;
  #pragma unroll
  for (int p=0;p<2;p++){
    int t = p*64 + lane;
    if (t < TT){
      float ts = entry + tc_of(t, exclA, totA, tBv);
      ts = fminf(fmaxf(ts,0.f),TotW);
      float prx,pry,prz;
      interp_at(ptsW, csW, coW, TotW, nvW, jmaxv, dir, ts, prx,pry,prz);
      o[t*3+0]=prx; o[t*3+1]=pry; o[t*3+2]=prz;
    }
  }
}

extern "C" void kernel_launch(void* const* d_in, const int* in_sizes, int n_in,
                              void* d_out, int out_size, void* d_ws, size_t ws_size,
                              hipStream_t stream) {
  const float* traj = (const float*)d_in[0];
  const float* rp   = (const float*)d_in[1];
  const void*  mask = d_in[2];
  float* ws   = (float*)d_ws;      // NN*96 floats
  float* out  = (float*)d_out;
  hipLaunchKernelGGL(fused_all, dim3(NN), dim3(1024), 0, stream,
                     traj, rp, mask, ws, out);
}